// Round 3
// baseline (287.847 us; speedup 1.0000x reference)
//
#include <hip/hip_runtime.h>

#define N_NODES 50000
#define N_EDGES 800000
#define D1 64
#define D2 32
#define N_CLASSES 6
#define N_GRAPHS 128
#define CAP 64       // per-node src bucket capacity == wave size; deg max ~45 << 64
#define GB 782       // ceil(50000/64) for 16x16 mm tiles (mm L0 in fused kernel)
#define AGB 782      // ceil(50000/64): agg_gru blocks (4 waves x 16 nodes)

// ---- two-level binned fill (replaces 800k scattered u16 stores / 800k global atomics) ----
#define NBINS 196    // ceil(50000/256): coarse bin = dst>>8 (256 nodes per bin)
#define BCAP 6144    // per-bin global run capacity (mean 4081, >16 sigma headroom)
#define EPB 4096     // edges per phase-1 fill block
#define NFILLB 196   // ceil(800000/4096)
#define LCAP 48      // per-(block,bin) LDS capacity (mean 20.9, ~6 sigma; overflow -> direct)
#define FH_BLOCKS (NFILLB + GB + 128 + 1)

typedef unsigned short u16;
typedef unsigned int u32;
typedef __attribute__((ext_vector_type(4))) int i32x4;
typedef __attribute__((ext_vector_type(4))) unsigned int u32x4;
typedef __attribute__((ext_vector_type(8))) short bf16x8;
typedef __attribute__((ext_vector_type(4))) float f32x4;

__device__ __forceinline__ float bf2f(u16 b) {
    u32 u = ((u32)b) << 16;
    float f;
    __builtin_memcpy(&f, &u, 4);
    return f;
}
__device__ __forceinline__ u16 f2bf(float f) {
    u32 u;
    __builtin_memcpy(&u, &f, 4);
    u32 r = (u + 0x7fffu + ((u >> 16) & 1u)) >> 16;
    return (u16)r;
}
__device__ __forceinline__ void split8(const float* v, bf16x8& hi, bf16x8& lo) {
#pragma unroll
    for (int j = 0; j < 8; ++j) {
        u16 h = f2bf(v[j]);
        hi[j] = (short)h;
        lo[j] = (short)f2bf(v[j] - bf2f(h));
    }
}
__device__ __forceinline__ void round8(const float* v, bf16x8& b) {
#pragma unroll
    for (int j = 0; j < 8; ++j) b[j] = (short)f2bf(v[j]);
}
__device__ __forceinline__ float sigmoidf_(float x) {
    return 1.0f / (1.0f + __expf(-x));
}
__device__ __forceinline__ float tanhf_(float x) {
    return 1.0f - 2.0f / (__expf(2.0f * x) + 1.0f);
}

// ===== fused: phase-1 binned edge scatter + pack + mm L0 =====
// Phase-1 fill: block bins 4096 edges into LDS by dst>>8, then flushes each bin
// as ONE coalesced run via a single global atomicAdd per (block,bin).
// B packed (single bf16) for 16x16x32 fragments:
//   idx=(step*16+nt)*512+lane*8+j,
//   value=Blog[k=step*32+(lane>>4)*8+j][n=nt*16+(lane&15)], step in 0..3, nt in 0..15.
__global__ __launch_bounds__(256) void fused_head_kernel(
        const int* __restrict__ ei, u32* __restrict__ binned, u32* __restrict__ binCursor,
        const float* __restrict__ x, const float* __restrict__ W,
        const float* __restrict__ wih, const float* __restrict__ whh,
        const float* __restrict__ bih, const float* __restrict__ bhh,
        short* __restrict__ Bh, float* __restrict__ bias4,
        u16* __restrict__ m16) {
    __shared__ u32 cnt[NBINS];
    __shared__ u32 base[NBINS];
    __shared__ u32 buck[NBINS][LCAP];  // 37.6 KB
    int b = blockIdx.x;
    int tid = threadIdx.x;
    if (b < NFILLB) {
        for (int i = tid; i < NBINS; i += 256) cnt[i] = 0;
        __syncthreads();
        int e0 = b * EPB;
        int nq = (min(EPB, N_EDGES - e0)) >> 2;  // 4096 and 1280 both div by 4
        const i32x4* s4 = (const i32x4*)ei + (e0 >> 2);
        const i32x4* d4 = (const i32x4*)(ei + N_EDGES) + (e0 >> 2);
#pragma unroll
        for (int ch = 0; ch < 4; ++ch) {
            int i = ch * 256 + tid;
            if (i < nq) {
                i32x4 ss = s4[i];
                i32x4 dd = d4[i];
#pragma unroll
                for (int j = 0; j < 4; ++j) {
                    int s = ss[j];
                    int d = dd[j];
                    int bin = d >> 8;
                    u32 pay = ((u32)s << 8) | (u32)(d & 255);
                    u32 p = atomicAdd(&cnt[bin], 1u);
                    if (p < LCAP) buck[bin][p] = pay;
                    else {  // astronomically rare; keeps correctness deterministic-safe
                        u32 q = atomicAdd(&binCursor[bin], 1u);
                        if (q < BCAP) binned[bin * BCAP + q] = pay;
                    }
                }
            }
        }
        __syncthreads();
        int lane = tid & 63, wv = tid >> 6;
        // each wave owns 49 bins; lane-parallel cursor reservations (one atomic latency)
        if (lane < 49) {
            int bin = wv * 49 + lane;
            u32 c = cnt[bin];
            c = c < (u32)LCAP ? c : (u32)LCAP;
            base[bin] = atomicAdd(&binCursor[bin], c);
        }
        __syncthreads();
        // coalesced run stores, fire-and-forget
        for (int idx = 0; idx < 49; ++idx) {
            int bin = wv * 49 + idx;
            u32 c = cnt[bin];
            c = c < (u32)LCAP ? c : (u32)LCAP;
            if ((u32)lane < c) {
                u32 pos = base[bin] + lane;
                if (pos < BCAP) binned[bin * BCAP + pos] = buck[bin][lane];
            }
        }
        return;
    }
    int ob = b - NFILLB;
    if (ob < GB) {
        // ---- mm L0: m = x @ W0 (A split bf16, W single bf16; out m16 bf16) ----
        int lane = tid & 63;
        int wv = tid >> 6;
        int node0 = ob * 64 + wv * 16;
        if (node0 >= N_NODES) return;
        int c0 = lane & 15, qr = lane >> 4;
        f32x4 acc[4];
#pragma unroll
        for (int nt = 0; nt < 4; ++nt) acc[nt] = (f32x4){0.f, 0.f, 0.f, 0.f};
#pragma unroll
        for (int kt = 0; kt < 2; ++kt) {
            int aoff = (node0 + c0) * 64 + kt * 32 + qr * 8;
            float tmp[8];
#pragma unroll
            for (int j = 0; j < 8; ++j) tmp[j] = x[aoff + j];
            bf16x8 ah, al;
            split8(tmp, ah, al);
            int k0 = kt * 32 + qr * 8;
#pragma unroll
            for (int nt = 0; nt < 4; ++nt) {
                int n = nt * 16 + c0;
                float wt[8];
#pragma unroll
                for (int j = 0; j < 8; ++j) wt[j] = W[(k0 + j) * 64 + n];
                bf16x8 bb;
                round8(wt, bb);
                acc[nt] = __builtin_amdgcn_mfma_f32_16x16x32_bf16(ah, bb, acc[nt], 0, 0, 0);
                acc[nt] = __builtin_amdgcn_mfma_f32_16x16x32_bf16(al, bb, acc[nt], 0, 0, 0);
            }
        }
#pragma unroll
        for (int nt = 0; nt < 4; ++nt)
#pragma unroll
            for (int r = 0; r < 4; ++r)
                m16[(node0 + qr * 4 + r) * 64 + nt * 16 + c0] = f2bf(acc[nt][r]);
    } else if (ob < GB + 128) {
        // ---- pack GRU B (single bf16) in 16x16x32 fragment order ----
        int idx = (ob - GB) * 256 + tid;   // 0..32767, one short each
        int j = idx & 7;
        int lane = (idx >> 3) & 63;
        int nt = (idx >> 9) & 15;
        int step = idx >> 13;              // 0..3
        int k = step * 32 + (lane >> 4) * 8 + j;   // logical K 0..127 ([agg(64) | h(64)])
        int n = nt * 16 + (lane & 15);             // gate col 0..255
        int g = n >> 6, d = n & 63;
        float v;
        if (g == 0)      v = (k < 64) ? wih[d * 64 + k] : whh[d * 64 + (k - 64)];
        else if (g == 1) v = (k < 64) ? wih[(64 + d) * 64 + k] : whh[(64 + d) * 64 + (k - 64)];
        else if (g == 2) v = (k < 64) ? wih[(128 + d) * 64 + k] : 0.f;
        else             v = (k < 64) ? 0.f : whh[(128 + d) * 64 + (k - 64)];
        Bh[idx] = (short)f2bf(v);
    } else {
        int j = tid;
        if (j < 64) {
            bias4[j] = bih[j] + bhh[j];
            bias4[64 + j] = bih[64 + j] + bhh[64 + j];
            bias4[128 + j] = bih[128 + j];
            bias4[192 + j] = bhh[128 + j];
        }
    }
}

// ===== phase 2: block per coarse bin; build per-node buckets in LDS, write
// srcidx slab (32KB contiguous) + deg fully coalesced. Replaces the deg memset. =====
__global__ __launch_bounds__(256) void bucket_kernel(
        const u32* __restrict__ binned, const u32* __restrict__ binCursor,
        int* __restrict__ deg, u16* __restrict__ srcidx) {
    __shared__ u32 ndeg[256];
    __shared__ __align__(16) u16 nb[256][CAP];  // 32 KB
    int bin = blockIdx.x;
    int tid = threadIdx.x;
    ndeg[tid] = 0;
    __syncthreads();
    int c = (int)binCursor[bin];
    if (c > BCAP) c = BCAP;
    const u32* src = binned + bin * BCAP;
    for (int i = tid; i < c; i += 256) {
        u32 pay = src[i];
        int dl = pay & 255;
        u32 p = atomicAdd(&ndeg[dl], 1u);
        if (p < CAP) nb[dl][p] = (u16)(pay >> 8);
    }
    __syncthreads();
    int node0 = bin * 256;
    int nn = N_NODES - node0;
    if (nn > 256) nn = 256;
    // coalesced vec4 slab store (unfilled slots carry garbage; gather never selects k>=deg)
    u32x4* dst16 = (u32x4*)(srcidx + (size_t)node0 * CAP);
    const u32x4* src16 = (const u32x4*)nb;
    int tot = nn * 8;  // nn*64 u16 = nn*8 u32x4
    for (int i = tid; i < tot; i += 256) dst16[i] = src16[i];
    if (tid < nn) {
        u32 d = ndeg[tid];
        deg[node0 + tid] = (int)(d < (u32)CAP ? d : (u32)CAP);
    }
}

// ===== fused agg + GRU (16x16x32 MFMA): wave = 16 nodes, 4 waves/block, no barriers.
// Phase 1 (gather): wave gathers/sums m16 rows for its 16 nodes (half-wave dword
// scheme, as the old agg_kernel) and transposes the f32 result through a
// wave-private LDS tile [16][68] (stride 68: 16B-aligned rows, <=2-way banks).
// Phase 2 (GRU): A split bf16 from tile (k 0..63) and hin f32 (k 64..127,
// split8 in-register); B single bf16 from global Bh (L2-hot, 64KB).
// Kills the aghi/aglo 25.6MB/layer round-trip + hhi/hlo entirely.
// A: row=lane&15, k=(lane>>4)*8+j. C/D: col=lane&15, row=(lane>>4)*4+reg.
// acc[nt] nt=0..15: gates [r(0..3) | z(4..7) | i_n(8..11) | h_n(12..15)] x 16 cols.
// DO_MM: fused next-layer mm through the same tile (agg values dead by then);
// m16 OUT must be a different buffer than m16 IN (other blocks still gathering).
template <bool DO_MM>
__global__ __launch_bounds__(256) void agg_gru(
        const u16* __restrict__ m16_in, const int* __restrict__ deg,
        const u16* __restrict__ srcidx,
        const short* __restrict__ Bh, const float* __restrict__ bias4,
        const float* hin,   // x (L0) or h (L1; aliases hout — lane-private rows)
        float* hout,
        const float* __restrict__ Wnext, u16* __restrict__ m16_out) {
    __shared__ float tile[4][16][68];  // 17.4 KB, wave-private slabs
    int tid = threadIdx.x;
    int lane = tid & 63;
    int wv = tid >> 6;
    int base = blockIdx.x * 64 + wv * 16;  // wave's first node
    int c = lane & 15, q = lane >> 4;      // q in 0..3
    int half = lane >> 5, l = lane & 31;
    float (*T)[68] = tile[wv];

    // ---- preload degree + src buckets for the 16 nodes (all loads in flight) ----
    int nb0 = base + c;
    if (nb0 > N_NODES - 1) nb0 = N_NODES - 1;
    int dg = deg[nb0];  // lane i<16 holds deg[base+i]
    int bvArr[16];
#pragma unroll
    for (int i = 0; i < 16; ++i) {
        int node = base + i;
        if (node > N_NODES - 1) node = N_NODES - 1;
        bvArr[i] = (int)srcidx[node * CAP + lane];
    }

    // ---- gather+agg per node; transpose into wave-private tile ----
    const u32* m32 = (const u32*)m16_in;
#pragma unroll
    for (int i = 0; i < 16; ++i) {
        int cnt = __shfl(dg, i);
        float a0 = 0.f, a1 = 0.f;
        int k = half;
        for (; k + 6 < cnt; k += 8) {
            int s0 = __shfl(bvArr[i], k);
            int s1 = __shfl(bvArr[i], k + 2);
            int s2 = __shfl(bvArr[i], k + 4);
            int s3 = __shfl(bvArr[i], k + 6);
            u32 d0 = m32[s0 * 32 + l];
            u32 d1 = m32[s1 * 32 + l];
            u32 d2 = m32[s2 * 32 + l];
            u32 d3 = m32[s3 * 32 + l];
            a0 += bf2f((u16)d0) + bf2f((u16)d1) + bf2f((u16)d2) + bf2f((u16)d3);
            a1 += bf2f((u16)(d0 >> 16)) + bf2f((u16)(d1 >> 16)) +
                  bf2f((u16)(d2 >> 16)) + bf2f((u16)(d3 >> 16));
        }
        for (; k < cnt; k += 2) {
            int s = __shfl(bvArr[i], k);
            u32 d = m32[s * 32 + l];
            a0 += bf2f((u16)d);
            a1 += bf2f((u16)(d >> 16));
        }
        a0 += __shfl_xor(a0, 32);
        a1 += __shfl_xor(a1, 32);
        if (half == 0) {  // cols {2l, 2l+1}: 1-way banks at stride 68
            T[i][2 * l] = a0;
            T[i][2 * l + 1] = a1;
        }
    }

    // ---- GRU MFMA ----
    int rowA = base + c;
    if (rowA > N_NODES - 1) rowA = N_NODES - 1;
    f32x4 acc[16];
#pragma unroll
    for (int nt = 0; nt < 16; ++nt) acc[nt] = (f32x4){0.f, 0.f, 0.f, 0.f};

#pragma unroll
    for (int s = 0; s < 4; ++s) {  // logical K: s 0-1 = agg (tile), s 2-3 = h (hin f32)
        float tmp[8];
#pragma unroll
        for (int j = 0; j < 8; ++j)
            tmp[j] = (s < 2) ? T[c][s * 32 + q * 8 + j]
                             : hin[rowA * 64 + (s - 2) * 32 + q * 8 + j];
        bf16x8 ah, al;
        split8(tmp, ah, al);
#pragma unroll
        for (int nt = 0; nt < 16; ++nt) {
            bf16x8 bb = *(const bf16x8*)(Bh + (s * 16 + nt) * 512 + lane * 8);
            acc[nt] = __builtin_amdgcn_mfma_f32_16x16x32_bf16(ah, bb, acc[nt], 0, 0, 0);
            acc[nt] = __builtin_amdgcn_mfma_f32_16x16x32_bf16(al, bb, acc[nt], 0, 0, 0);
        }
    }

    // ---- gates epilogue: col j=jt*16+c uses acc {jt, 4+jt, 8+jt, 12+jt} ----
#pragma unroll
    for (int reg = 0; reg < 4; ++reg) {
        int R = q * 4 + reg;  // local row 0..15
        int row = base + R;
        bool ok = row < N_NODES;
        int rrow = ok ? row : N_NODES - 1;  // clamp reads; writes guarded
#pragma unroll
        for (int jt = 0; jt < 4; ++jt) {
            int j = jt * 16 + c;
            float rr = sigmoidf_(acc[jt][reg] + bias4[j]);
            float zz = sigmoidf_(acc[4 + jt][reg] + bias4[64 + j]);
            float nn = tanhf_(acc[8 + jt][reg] + bias4[128 + j] +
                              rr * (acc[12 + jt][reg] + bias4[192 + j]));
            float ho = hin[rrow * 64 + j];
            float v = (1.f - zz) * nn + zz * ho;
            if (ok) hout[row * 64 + j] = v;
            if (DO_MM) T[R][j] = v;  // tile reuse; agg values fully consumed above
        }
    }

    if (DO_MM) {
        // mm next layer: m16_out[row] = h[row] @ Wnext (bf16 x bf16)
        f32x4 macc[4];
#pragma unroll
        for (int nt = 0; nt < 4; ++nt) macc[nt] = (f32x4){0.f, 0.f, 0.f, 0.f};
#pragma unroll
        for (int kt = 0; kt < 2; ++kt) {
            int k0 = kt * 32 + q * 8;
            float tmp[8];
#pragma unroll
            for (int j = 0; j < 8; ++j) tmp[j] = T[c][k0 + j];  // 2-way, free
            bf16x8 aa;
            round8(tmp, aa);
#pragma unroll
            for (int nt = 0; nt < 4; ++nt) {
                float wt[8];
#pragma unroll
                for (int j = 0; j < 8; ++j) wt[j] = Wnext[(k0 + j) * 64 + nt * 16 + c];
                bf16x8 bb;
                round8(wt, bb);
                macc[nt] = __builtin_amdgcn_mfma_f32_16x16x32_bf16(aa, bb, macc[nt], 0, 0, 0);
            }
        }
#pragma unroll
        for (int nt = 0; nt < 4; ++nt)
#pragma unroll
            for (int reg = 0; reg < 4; ++reg) {
                int row = base + q * 4 + reg;
                if (row < N_NODES)
                    m16_out[row * 64 + nt * 16 + c] = f2bf(macc[nt][reg]);
            }
    }
}

// ===== fused relu + segment-mean pool + fc1/relu/fc2/log_softmax; block per graph =====
__global__ __launch_bounds__(256) void poolhead_kernel(const float* __restrict__ h,
                                                       const int* __restrict__ batch,
                                                       const float* __restrict__ fc1w,
                                                       const float* __restrict__ fc1b,
                                                       const float* __restrict__ fc2w,
                                                       const float* __restrict__ fc2b,
                                                       float* __restrict__ out) {
    int g = blockIdx.x;
    int tid = threadIdx.x, lane = tid & 63, wv = tid >> 6;
    int lo, hi;
    {
        int a = 0, b = N_NODES;
        while (a < b) { int mid = (a + b) >> 1; if (batch[mid] < g) a = mid + 1; else b = mid; }
        lo = a;
    }
    {
        int a = lo, b = N_NODES;
        while (a < b) { int mid = (a + b) >> 1; if (batch[mid] < g + 1) a = mid + 1; else b = mid; }
        hi = a;
    }
    float acc = 0.f;
    for (int n = lo + wv; n < hi; n += 4) acc += fmaxf(h[n * 64 + lane], 0.f);
    __shared__ float red[4][64];
    __shared__ float pv[64];
    __shared__ float s1[32];
    __shared__ float s2[6];
    red[wv][lane] = acc;
    __syncthreads();
    if (tid < 64)
        pv[tid] = (red[0][tid] + red[1][tid] + red[2][tid] + red[3][tid]) /
                  fmaxf((float)(hi - lo), 1.f);
    __syncthreads();
    if (tid < 32) {
        float a2 = fc1b[tid];
#pragma unroll
        for (int j = 0; j < 64; ++j) a2 = fmaf(pv[j], fc1w[tid * 64 + j], a2);
        s1[tid] = fmaxf(a2, 0.f);
    }
    __syncthreads();
    if (tid < 6) {
        float a2 = fc2b[tid];
#pragma unroll
        for (int j = 0; j < 32; ++j) a2 = fmaf(s1[j], fc2w[tid * 32 + j], a2);
        s2[tid] = a2;
    }
    __syncthreads();
    if (tid == 0) {
        float mx = s2[0];
#pragma unroll
        for (int c = 1; c < 6; ++c) mx = fmaxf(mx, s2[c]);
        float se = 0.f;
#pragma unroll
        for (int c = 0; c < 6; ++c) se += __expf(s2[c] - mx);
        float lse = mx + __logf(se);
#pragma unroll
        for (int c = 0; c < 6; ++c) out[g * 6 + c] = s2[c] - lse;
    }
}

extern "C" void kernel_launch(void* const* d_in, const int* in_sizes, int n_in,
                              void* d_out, int out_size, void* d_ws, size_t ws_size,
                              hipStream_t stream) {
    const float* x    = (const float*)d_in[0];
    const int* ei     = (const int*)d_in[1];
    const int* batch  = (const int*)d_in[2];
    const float* W    = (const float*)d_in[3];
    const float* wih  = (const float*)d_in[4];
    const float* whh  = (const float*)d_in[5];
    const float* bih  = (const float*)d_in[6];
    const float* bhh  = (const float*)d_in[7];
    const float* fc1w = (const float*)d_in[8];
    const float* fc1b = (const float*)d_in[9];
    const float* fc2w = (const float*)d_in[10];
    const float* fc2b = (const float*)d_in[11];
    float* out = (float*)d_out;

    // ---- workspace layout ----
    float* h       = (float*)d_ws;               // 3.2M f
    float* bias4   = h + N_NODES * D1;           // 256 f
    int* deg       = (int*)(bias4 + 256);        // N_NODES
    u16* srcidx    = (u16*)(deg + N_NODES);      // N_NODES*CAP u16 = 6.4 MB
    size_t soff = ((size_t)(srcidx + N_NODES * CAP) + 15) & ~(size_t)15;
    u16* m16    = (u16*)soff;                    // 3.2M u16 (layer-0 m)
    u16* m16b   = m16 + N_NODES * D1;            // 3.2M u16 (layer-1 m)
    short* Bh   = (short*)(m16b + N_NODES * D1); // 32768 shorts
    u32* binCursor = (u32*)(Bh + 32768);         // NBINS u32
    // binned runs (4.8 MB) alias m16b: dead before agg_gru L0 writes m16b
    u32* binned = (u32*)m16b;

    hipMemsetAsync(binCursor, 0, NBINS * sizeof(u32), stream);
    // phase 1 (196 fill blocks, start immediately) + mm L0 + pack + bias
    fused_head_kernel<<<FH_BLOCKS, 256, 0, stream>>>(
        ei, binned, binCursor, x, W, wih, whh, bih, bhh, Bh, bias4, m16);
    // phase 2: per-bin bucket build, fully coalesced srcidx/deg writes
    bucket_kernel<<<NBINS, 256, 0, stream>>>(binned, binCursor, deg, srcidx);

    // layer 0: fused agg+gru (+ mm of layer 1 into m16b)
    agg_gru<true><<<AGB, 256, 0, stream>>>(
        m16, deg, srcidx, Bh, bias4, x, h, W + 4096, m16b);
    // layer 1: fused agg+gru (in-place h update; lane-private rows)
    agg_gru<false><<<AGB, 256, 0, stream>>>(
        m16b, deg, srcidx, Bh, bias4, h, h, nullptr, nullptr);

    poolhead_kernel<<<N_GRAPHS, 256, 0, stream>>>(h, batch, fc1w, fc1b, fc2w, fc2b, out);
}

// Round 6
// 284.764 us; speedup vs baseline: 1.0108x; 1.0108x over previous
//
#include <hip/hip_runtime.h>

#define N_NODES 50000
#define N_EDGES 800000
#define D1 64
#define D2 32
#define N_CLASSES 6
#define N_GRAPHS 128
#define CAP 64       // per-node src bucket capacity == wave size; deg max ~45 << 64
#define GB 782       // ceil(50000/64) for 16x16 mm tiles (mm L0 in fused kernel)
#define GRUT 3125    // 50000/16: per-wave gru tasks (16 rows each, exact)

// ---- two-level binned fill ----
#define NBINS 196    // ceil(50000/256): coarse bin = dst>>8 (256 nodes per bin)
#define BCAP 6144    // per-bin global run capacity (mean 4081, >16 sigma headroom)
#define EPB 4096     // edges per phase-1 fill block
#define NFILLB 196   // ceil(800000/4096)
#define LCAP 48      // per-(block,bin) LDS capacity (mean 20.9, ~6 sigma; overflow -> direct)
#define FH_BLOCKS (NFILLB + GB + 128 + 1)

typedef unsigned short u16;
typedef unsigned int u32;
typedef __attribute__((ext_vector_type(4))) int i32x4;
typedef __attribute__((ext_vector_type(4))) unsigned int u32x4;
typedef __attribute__((ext_vector_type(8))) short bf16x8;
typedef __attribute__((ext_vector_type(4))) float f32x4;

__device__ __forceinline__ float bf2f(u16 b) {
    u32 u = ((u32)b) << 16;
    float f;
    __builtin_memcpy(&f, &u, 4);
    return f;
}
__device__ __forceinline__ u16 f2bf(float f) {
    u32 u;
    __builtin_memcpy(&u, &f, 4);
    u32 r = (u + 0x7fffu + ((u >> 16) & 1u)) >> 16;
    return (u16)r;
}
__device__ __forceinline__ void split8(const float* v, bf16x8& hi, bf16x8& lo) {
#pragma unroll
    for (int j = 0; j < 8; ++j) {
        u16 h = f2bf(v[j]);
        hi[j] = (short)h;
        lo[j] = (short)f2bf(v[j] - bf2f(h));
    }
}
__device__ __forceinline__ void round8(const float* v, bf16x8& b) {
#pragma unroll
    for (int j = 0; j < 8; ++j) b[j] = (short)f2bf(v[j]);
}
__device__ __forceinline__ float sigmoidf_(float x) {
    return 1.0f / (1.0f + __expf(-x));
}
__device__ __forceinline__ float tanhf_(float x) {
    return 1.0f - 2.0f / (__expf(2.0f * x) + 1.0f);
}

// ===== fused: phase-1 binned edge scatter + pack + mm L0 (unchanged, known-good) =====
__global__ __launch_bounds__(256) void fused_head_kernel(
        const int* __restrict__ ei, u32* __restrict__ binned, u32* __restrict__ binCursor,
        const float* __restrict__ x, const float* __restrict__ W,
        const float* __restrict__ wih, const float* __restrict__ whh,
        const float* __restrict__ bih, const float* __restrict__ bhh,
        short* __restrict__ Bh, float* __restrict__ bias4,
        u16* __restrict__ m16) {
    __shared__ u32 cnt[NBINS];
    __shared__ u32 base[NBINS];
    __shared__ u32 buck[NBINS][LCAP];  // 37.6 KB
    int b = blockIdx.x;
    int tid = threadIdx.x;
    if (b < NFILLB) {
        for (int i = tid; i < NBINS; i += 256) cnt[i] = 0;
        __syncthreads();
        int e0 = b * EPB;
        int nq = (min(EPB, N_EDGES - e0)) >> 2;
        const i32x4* s4 = (const i32x4*)ei + (e0 >> 2);
        const i32x4* d4 = (const i32x4*)(ei + N_EDGES) + (e0 >> 2);
#pragma unroll
        for (int ch = 0; ch < 4; ++ch) {
            int i = ch * 256 + tid;
            if (i < nq) {
                i32x4 ss = s4[i];
                i32x4 dd = d4[i];
#pragma unroll
                for (int j = 0; j < 4; ++j) {
                    int s = ss[j];
                    int d = dd[j];
                    int bin = d >> 8;
                    u32 pay = ((u32)s << 8) | (u32)(d & 255);
                    u32 p = atomicAdd(&cnt[bin], 1u);
                    if (p < LCAP) buck[bin][p] = pay;
                    else {
                        u32 q = atomicAdd(&binCursor[bin], 1u);
                        if (q < BCAP) binned[bin * BCAP + q] = pay;
                    }
                }
            }
        }
        __syncthreads();
        int lane = tid & 63, wv = tid >> 6;
        if (lane < 49) {
            int bin = wv * 49 + lane;
            u32 c = cnt[bin];
            c = c < (u32)LCAP ? c : (u32)LCAP;
            base[bin] = atomicAdd(&binCursor[bin], c);
        }
        __syncthreads();
        for (int idx = 0; idx < 49; ++idx) {
            int bin = wv * 49 + idx;
            u32 c = cnt[bin];
            c = c < (u32)LCAP ? c : (u32)LCAP;
            if ((u32)lane < c) {
                u32 pos = base[bin] + lane;
                if (pos < BCAP) binned[bin * BCAP + pos] = buck[bin][lane];
            }
        }
        return;
    }
    int ob = b - NFILLB;
    if (ob < GB) {
        // ---- mm L0: m = x @ W0 (A split bf16, W single bf16; out m16 bf16) ----
        int lane = tid & 63;
        int wv = tid >> 6;
        int node0 = ob * 64 + wv * 16;
        if (node0 >= N_NODES) return;
        int c0 = lane & 15, qr = lane >> 4;
        f32x4 acc[4];
#pragma unroll
        for (int nt = 0; nt < 4; ++nt) acc[nt] = (f32x4){0.f, 0.f, 0.f, 0.f};
#pragma unroll
        for (int kt = 0; kt < 2; ++kt) {
            int aoff = (node0 + c0) * 64 + kt * 32 + qr * 8;
            float tmp[8];
#pragma unroll
            for (int j = 0; j < 8; ++j) tmp[j] = x[aoff + j];
            bf16x8 ah, al;
            split8(tmp, ah, al);
            int k0 = kt * 32 + qr * 8;
#pragma unroll
            for (int nt = 0; nt < 4; ++nt) {
                int n = nt * 16 + c0;
                float wt[8];
#pragma unroll
                for (int j = 0; j < 8; ++j) wt[j] = W[(k0 + j) * 64 + n];
                bf16x8 bb;
                round8(wt, bb);
                acc[nt] = __builtin_amdgcn_mfma_f32_16x16x32_bf16(ah, bb, acc[nt], 0, 0, 0);
                acc[nt] = __builtin_amdgcn_mfma_f32_16x16x32_bf16(al, bb, acc[nt], 0, 0, 0);
            }
        }
#pragma unroll
        for (int nt = 0; nt < 4; ++nt)
#pragma unroll
            for (int r = 0; r < 4; ++r)
                m16[(node0 + qr * 4 + r) * 64 + nt * 16 + c0] = f2bf(acc[nt][r]);
    } else if (ob < GB + 128) {
        // ---- pack GRU B (single bf16) in 16x16x32 fragment order ----
        int idx = (ob - GB) * 256 + tid;
        int j = idx & 7;
        int lane = (idx >> 3) & 63;
        int nt = (idx >> 9) & 15;
        int step = idx >> 13;
        int k = step * 32 + (lane >> 4) * 8 + j;
        int n = nt * 16 + (lane & 15);
        int g = n >> 6, d = n & 63;
        float v;
        if (g == 0)      v = (k < 64) ? wih[d * 64 + k] : whh[d * 64 + (k - 64)];
        else if (g == 1) v = (k < 64) ? wih[(64 + d) * 64 + k] : whh[(64 + d) * 64 + (k - 64)];
        else if (g == 2) v = (k < 64) ? wih[(128 + d) * 64 + k] : 0.f;
        else             v = (k < 64) ? 0.f : whh[(128 + d) * 64 + (k - 64)];
        Bh[idx] = (short)f2bf(v);
    } else {
        int j = tid;
        if (j < 64) {
            bias4[j] = bih[j] + bhh[j];
            bias4[64 + j] = bih[64 + j] + bhh[64 + j];
            bias4[128 + j] = bih[128 + j];
            bias4[192 + j] = bhh[128 + j];
        }
    }
}

// ===== phase 2: block per coarse bin; per-node buckets in LDS, coalesced slab out =====
__global__ __launch_bounds__(256) void bucket_kernel(
        const u32* __restrict__ binned, const u32* __restrict__ binCursor,
        int* __restrict__ deg, u16* __restrict__ srcidx) {
    __shared__ u32 ndeg[256];
    __shared__ __align__(16) u16 nb[256][CAP];  // 32 KB
    int bin = blockIdx.x;
    int tid = threadIdx.x;
    ndeg[tid] = 0;
    __syncthreads();
    int c = (int)binCursor[bin];
    if (c > BCAP) c = BCAP;
    const u32* src = binned + bin * BCAP;
    for (int i = tid; i < c; i += 256) {
        u32 pay = src[i];
        int dl = pay & 255;
        u32 p = atomicAdd(&ndeg[dl], 1u);
        if (p < CAP) nb[dl][p] = (u16)(pay >> 8);
    }
    __syncthreads();
    int node0 = bin * 256;
    int nn = N_NODES - node0;
    if (nn > 256) nn = 256;
    u32x4* dst16 = (u32x4*)(srcidx + (size_t)node0 * CAP);
    const u32x4* src16 = (const u32x4*)nb;
    int tot = nn * 8;
    for (int i = tid; i < tot; i += 256) dst16[i] = src16[i];
    if (tid < nn) {
        u32 d = ndeg[tid];
        deg[node0 + tid] = (int)(d < (u32)CAP ? d : (u32)CAP);
    }
}

// ===== agg: wave per node; half-wave dword gather; OUT: aggf f32.
// (gru re-splits in-register via split8 — bitwise identical to the old
// stored hi/lo bf16 pair, same bytes/node, but kills the hhi/hlo buffers.) =====
__global__ __launch_bounds__(256) void agg_kernel(const u16* __restrict__ m16,
                                                  const int* __restrict__ deg,
                                                  const u16* __restrict__ srcidx,
                                                  float* __restrict__ aggf) {
    int lane = threadIdx.x & 63;
    int node = blockIdx.x * 4 + (threadIdx.x >> 6);  // grid exact: 50000/4
    int cnt = __builtin_amdgcn_readfirstlane(deg[node]);
    cnt = cnt < CAP ? cnt : CAP;
    int bv = (int)srcidx[node * CAP + lane];
    int half = lane >> 5;
    int l = lane & 31;
    const u32* m32 = (const u32*)m16;
    float a0 = 0.f, a1 = 0.f;
    int k = half;
    for (; k + 6 < cnt; k += 8) {
        int s0 = __shfl(bv, k);
        int s1 = __shfl(bv, k + 2);
        int s2 = __shfl(bv, k + 4);
        int s3 = __shfl(bv, k + 6);
        u32 d0 = m32[s0 * 32 + l];
        u32 d1 = m32[s1 * 32 + l];
        u32 d2 = m32[s2 * 32 + l];
        u32 d3 = m32[s3 * 32 + l];
        a0 += bf2f((u16)d0) + bf2f((u16)d1) + bf2f((u16)d2) + bf2f((u16)d3);
        a1 += bf2f((u16)(d0 >> 16)) + bf2f((u16)(d1 >> 16)) +
              bf2f((u16)(d2 >> 16)) + bf2f((u16)(d3 >> 16));
    }
    for (; k < cnt; k += 2) {
        int s = __shfl(bv, k);
        u32 d = m32[s * 32 + l];
        a0 += bf2f((u16)d);
        a1 += bf2f((u16)(d >> 16));
    }
    a0 += __shfl_xor(a0, 32);
    a1 += __shfl_xor(a1, 32);
    if (half == 0) {  // cols {2l, 2l+1}; coalesced 256B per node
        float2 st;
        st.x = a0;
        st.y = a1;
        ((float2*)aggf)[node * 32 + l] = st;
    }
}

// ===== GRU on 16x16x32 MFMA: one wave = 16 rows (50000 = 3125*16, guard only on
// the block-level extra tasks). A split bf16 in-register from f32 sources
// (aggf k0..63, hin k64..127); B single bf16 from Bh (L2-hot 64KB).
// A: row=lane&15, k=(lane>>4)*8+j. C/D: col=lane&15, row=(lane>>4)*4+reg.
// acc[nt] nt=0..15: gates [r(0..3) | z(4..7) | i_n(8..11) | h_n(12..15)] x 16 cols. =====
template <bool DO_MM>
__global__ __launch_bounds__(256) void gru_kernel(
        const float* __restrict__ aggf, const short* __restrict__ Bh,
        const float* __restrict__ bias4,
        const float* hin,  // x (L0) or h (L1, in-place: waves touch only own rows)
        float* hout,
        const float* __restrict__ Wnext, u16* __restrict__ m16) {
    __shared__ __align__(16) float tiles[DO_MM ? 4 * 16 * 65 : 4];
    int tid = threadIdx.x;
    int lane = tid & 63;
    int wv = tid >> 6;
    int wtask = blockIdx.x * 4 + wv;
    if (wtask >= GRUT) return;
    int node0 = wtask * 16;
    int c = lane & 15, q = lane >> 4;  // q in 0..3
    int rowA = node0 + c;
    float* myTile = tiles + (DO_MM ? wv * 16 * 65 : 0);

    f32x4 acc[16];
#pragma unroll
    for (int nt = 0; nt < 16; ++nt) acc[nt] = (f32x4){0.f, 0.f, 0.f, 0.f};

#pragma unroll
    for (int step = 0; step < 4; ++step) {  // logical K: steps 0-1 = agg, 2-3 = h
        const float* src = (step < 2) ? aggf : hin;
        int aoff = rowA * 64 + (step & 1) * 32 + q * 8;
        float tmp[8];
#pragma unroll
        for (int j = 0; j < 8; ++j) tmp[j] = src[aoff + j];
        bf16x8 ah, al;
        split8(tmp, ah, al);
#pragma unroll
        for (int nt = 0; nt < 16; ++nt) {
            bf16x8 bb = *(const bf16x8*)(Bh + (step * 16 + nt) * 512 + lane * 8);
            acc[nt] = __builtin_amdgcn_mfma_f32_16x16x32_bf16(ah, bb, acc[nt], 0, 0, 0);
            acc[nt] = __builtin_amdgcn_mfma_f32_16x16x32_bf16(al, bb, acc[nt], 0, 0, 0);
        }
    }

    // gates: output col j=jt*16+c uses acc {jt, 4+jt, 8+jt, 12+jt} (r, z, i_n, h_n)
#pragma unroll
    for (int reg = 0; reg < 4; ++reg) {
        int R = q * 4 + reg;  // local row 0..15
        int row = node0 + R;
#pragma unroll
        for (int jt = 0; jt < 4; ++jt) {
            int j = jt * 16 + c;
            float rr = sigmoidf_(acc[jt][reg] + bias4[j]);
            float zz = sigmoidf_(acc[4 + jt][reg] + bias4[64 + j]);
            float nn = tanhf_(acc[8 + jt][reg] + bias4[128 + j] +
                              rr * (acc[12 + jt][reg] + bias4[192 + j]));
            float ho = hin[row * 64 + j];
            float v = (1.f - zz) * nn + zz * ho;
            hout[row * 64 + j] = v;
            if (DO_MM) myTile[R * 65 + j] = v;  // <=4-way bank alias on 16 stores
        }
    }

    if (DO_MM) {
        // mm next layer: m16[row] = h[row] @ Wnext (bf16 x bf16)
        f32x4 macc[4];
#pragma unroll
        for (int nt = 0; nt < 4; ++nt) macc[nt] = (f32x4){0.f, 0.f, 0.f, 0.f};
#pragma unroll
        for (int kt = 0; kt < 2; ++kt) {
            int k0 = kt * 32 + q * 8;
            float tmp[8];
#pragma unroll
            for (int j = 0; j < 8; ++j) tmp[j] = myTile[c * 65 + k0 + j];  // 2-way, free
            bf16x8 aa;
            round8(tmp, aa);
#pragma unroll
            for (int nt = 0; nt < 4; ++nt) {
                float wt[8];
#pragma unroll
                for (int j = 0; j < 8; ++j) wt[j] = Wnext[(k0 + j) * 64 + nt * 16 + c];
                bf16x8 bb;
                round8(wt, bb);
                macc[nt] = __builtin_amdgcn_mfma_f32_16x16x32_bf16(aa, bb, macc[nt], 0, 0, 0);
            }
        }
#pragma unroll
        for (int nt = 0; nt < 4; ++nt)
#pragma unroll
            for (int reg = 0; reg < 4; ++reg)
                m16[(node0 + q * 4 + reg) * 64 + nt * 16 + c] = f2bf(macc[nt][reg]);
    }
}

// ===== fused relu + segment-mean pool + fc1/relu/fc2/log_softmax; block per graph =====
__global__ __launch_bounds__(256) void poolhead_kernel(const float* __restrict__ h,
                                                       const int* __restrict__ batch,
                                                       const float* __restrict__ fc1w,
                                                       const float* __restrict__ fc1b,
                                                       const float* __restrict__ fc2w,
                                                       const float* __restrict__ fc2b,
                                                       float* __restrict__ out) {
    int g = blockIdx.x;
    int tid = threadIdx.x, lane = tid & 63, wv = tid >> 6;
    int lo, hi;
    {
        int a = 0, b = N_NODES;
        while (a < b) { int mid = (a + b) >> 1; if (batch[mid] < g) a = mid + 1; else b = mid; }
        lo = a;
    }
    {
        int a = lo, b = N_NODES;
        while (a < b) { int mid = (a + b) >> 1; if (batch[mid] < g + 1) a = mid + 1; else b = mid; }
        hi = a;
    }
    float acc = 0.f;
    for (int n = lo + wv; n < hi; n += 4) acc += fmaxf(h[n * 64 + lane], 0.f);
    __shared__ float red[4][64];
    __shared__ float pv[64];
    __shared__ float s1[32];
    __shared__ float s2[6];
    red[wv][lane] = acc;
    __syncthreads();
    if (tid < 64)
        pv[tid] = (red[0][tid] + red[1][tid] + red[2][tid] + red[3][tid]) /
                  fmaxf((float)(hi - lo), 1.f);
    __syncthreads();
    if (tid < 32) {
        float a2 = fc1b[tid];
#pragma unroll
        for (int j = 0; j < 64; ++j) a2 = fmaf(pv[j], fc1w[tid * 64 + j], a2);
        s1[tid] = fmaxf(a2, 0.f);
    }
    __syncthreads();
    if (tid < 6) {
        float a2 = fc2b[tid];
#pragma unroll
        for (int j = 0; j < 32; ++j) a2 = fmaf(s1[j], fc2w[tid * 32 + j], a2);
        s2[tid] = a2;
    }
    __syncthreads();
    if (tid == 0) {
        float mx = s2[0];
#pragma unroll
        for (int c = 1; c < 6; ++c) mx = fmaxf(mx, s2[c]);
        float se = 0.f;
#pragma unroll
        for (int c = 0; c < 6; ++c) se += __expf(s2[c] - mx);
        float lse = mx + __logf(se);
#pragma unroll
        for (int c = 0; c < 6; ++c) out[g * 6 + c] = s2[c] - lse;
    }
}

extern "C" void kernel_launch(void* const* d_in, const int* in_sizes, int n_in,
                              void* d_out, int out_size, void* d_ws, size_t ws_size,
                              hipStream_t stream) {
    const float* x    = (const float*)d_in[0];
    const int* ei     = (const int*)d_in[1];
    const int* batch  = (const int*)d_in[2];
    const float* W    = (const float*)d_in[3];
    const float* wih  = (const float*)d_in[4];
    const float* whh  = (const float*)d_in[5];
    const float* bih  = (const float*)d_in[6];
    const float* bhh  = (const float*)d_in[7];
    const float* fc1w = (const float*)d_in[8];
    const float* fc1b = (const float*)d_in[9];
    const float* fc2w = (const float*)d_in[10];
    const float* fc2b = (const float*)d_in[11];
    float* out = (float*)d_out;

    // ---- workspace layout ----
    float* h       = (float*)d_ws;               // 12.8 MB
    float* bias4   = h + N_NODES * D1;           // 256 f
    int* deg       = (int*)(bias4 + 256);        // N_NODES
    u16* srcidx    = (u16*)(deg + N_NODES);      // 6.4 MB
    size_t soff = ((size_t)(srcidx + N_NODES * CAP) + 15) & ~(size_t)15;
    u16* m16    = (u16*)soff;                    // 6.4 MB
    float* aggf = (float*)(m16 + N_NODES * D1);  // 12.8 MB f32 agg
    short* Bh   = (short*)(aggf + N_NODES * D1); // 64 KB
    u32* binCursor = (u32*)(Bh + 32768);         // NBINS u32
    // binned runs (4.8 MB) alias the start of aggf: consumed by bucket_kernel,
    // aggf first written by agg_kernel strictly after (kernel boundary).
    u32* binned = (u32*)aggf;
    const float* Wnext = W + 4096;

    hipMemsetAsync(binCursor, 0, NBINS * sizeof(u32), stream);
    // phase 1 (196 fill blocks, start immediately) + mm L0 + pack + bias
    fused_head_kernel<<<FH_BLOCKS, 256, 0, stream>>>(
        ei, binned, binCursor, x, W, wih, whh, bih, bhh, Bh, bias4, m16);
    // phase 2: per-bin bucket build, fully coalesced srcidx/deg writes
    bucket_kernel<<<NBINS, 256, 0, stream>>>(binned, binCursor, deg, srcidx);

    // layer 0: agg -> gru (+ fused mm of layer 1 into m16)
    agg_kernel<<<N_NODES / 4, 256, 0, stream>>>(m16, deg, srcidx, aggf);
    gru_kernel<true><<<GB, 256, 0, stream>>>(aggf, Bh, bias4, x, h, Wnext, m16);
    // layer 1: agg -> gru (in-place h)
    agg_kernel<<<N_NODES / 4, 256, 0, stream>>>(m16, deg, srcidx, aggf);
    gru_kernel<false><<<GB, 256, 0, stream>>>(aggf, Bh, bias4, h, h, nullptr, nullptr);

    poolhead_kernel<<<N_GRAPHS, 256, 0, stream>>>(h, batch, fc1w, fc1b, fc2w, fc2b, out);
}

// Round 7
// 237.476 us; speedup vs baseline: 1.2121x; 1.1991x over previous
//
#include <hip/hip_runtime.h>

#define N_NODES 50000
#define N_EDGES 800000
#define D1 64
#define D2 32
#define N_CLASSES 6
#define N_GRAPHS 128
#define CAP 64       // per-node src bucket capacity == wave size; deg max ~45 << 64
#define GB 782       // ceil(50000/64) for 16x16 mm tiles (mm L0 in fused kernel)
#define GRUT 3125    // 50000/16: per-wave gru tasks (16 rows each, exact)

// ---- two-level binned fill ----
#define NBINS 196    // ceil(50000/256): coarse bin = dst>>8 (256 nodes per bin)
#define BCAP 6144    // per-bin global run capacity (mean 4081, >16 sigma headroom)
#define EPB 4096     // edges per phase-1 fill block
#define NFILLB 196   // ceil(800000/4096)
#define LCAP 48      // per-(block,bin) LDS capacity (mean 20.9, ~6 sigma; overflow -> direct)
#define FH_BLOCKS (NFILLB + GB + 128 + 16 + 1)  // fill + mm + Bh pack + Wp pack + bias

typedef unsigned short u16;
typedef unsigned int u32;
typedef __attribute__((ext_vector_type(4))) int i32x4;
typedef __attribute__((ext_vector_type(4))) unsigned int u32x4;
typedef __attribute__((ext_vector_type(8))) short bf16x8;
typedef __attribute__((ext_vector_type(4))) float f32x4;

__device__ __forceinline__ float bf2f(u16 b) {
    u32 u = ((u32)b) << 16;
    float f;
    __builtin_memcpy(&f, &u, 4);
    return f;
}
__device__ __forceinline__ u16 f2bf(float f) {
    u32 u;
    __builtin_memcpy(&u, &f, 4);
    u32 r = (u + 0x7fffu + ((u >> 16) & 1u)) >> 16;
    return (u16)r;
}
__device__ __forceinline__ void split8(const float* v, bf16x8& hi, bf16x8& lo) {
#pragma unroll
    for (int j = 0; j < 8; ++j) {
        u16 h = f2bf(v[j]);
        hi[j] = (short)h;
        lo[j] = (short)f2bf(v[j] - bf2f(h));
    }
}
__device__ __forceinline__ void round8(const float* v, bf16x8& b) {
#pragma unroll
    for (int j = 0; j < 8; ++j) b[j] = (short)f2bf(v[j]);
}
__device__ __forceinline__ float sigmoidf_(float x) {
    return 1.0f / (1.0f + __expf(-x));
}
__device__ __forceinline__ float tanhf_(float x) {
    return 1.0f - 2.0f / (__expf(2.0f * x) + 1.0f);
}

// ===== fused: phase-1 binned edge scatter + pack + mm L0 =====
__global__ __launch_bounds__(256) void fused_head_kernel(
        const int* __restrict__ ei, u32* __restrict__ binned, u32* __restrict__ binCursor,
        const float* __restrict__ x, const float* __restrict__ W,
        const float* __restrict__ wih, const float* __restrict__ whh,
        const float* __restrict__ bih, const float* __restrict__ bhh,
        short* __restrict__ Bh, short* __restrict__ Wp, float* __restrict__ bias4,
        u16* __restrict__ m16) {
    __shared__ u32 cnt[NBINS];
    __shared__ u32 base[NBINS];
    __shared__ u32 buck[NBINS][LCAP];  // 37.6 KB
    int b = blockIdx.x;
    int tid = threadIdx.x;
    if (b < NFILLB) {
        for (int i = tid; i < NBINS; i += 256) cnt[i] = 0;
        __syncthreads();
        int e0 = b * EPB;
        int nq = (min(EPB, N_EDGES - e0)) >> 2;
        const i32x4* s4 = (const i32x4*)ei + (e0 >> 2);
        const i32x4* d4 = (const i32x4*)(ei + N_EDGES) + (e0 >> 2);
#pragma unroll
        for (int ch = 0; ch < 4; ++ch) {
            int i = ch * 256 + tid;
            if (i < nq) {
                i32x4 ss = s4[i];
                i32x4 dd = d4[i];
#pragma unroll
                for (int j = 0; j < 4; ++j) {
                    int s = ss[j];
                    int d = dd[j];
                    int bin = d >> 8;
                    u32 pay = ((u32)s << 8) | (u32)(d & 255);
                    u32 p = atomicAdd(&cnt[bin], 1u);
                    if (p < LCAP) buck[bin][p] = pay;
                    else {
                        u32 q = atomicAdd(&binCursor[bin], 1u);
                        if (q < BCAP) binned[bin * BCAP + q] = pay;
                    }
                }
            }
        }
        __syncthreads();
        int lane = tid & 63, wv = tid >> 6;
        if (lane < 49) {
            int bin = wv * 49 + lane;
            u32 c = cnt[bin];
            c = c < (u32)LCAP ? c : (u32)LCAP;
            base[bin] = atomicAdd(&binCursor[bin], c);
        }
        __syncthreads();
        for (int idx = 0; idx < 49; ++idx) {
            int bin = wv * 49 + idx;
            u32 c = cnt[bin];
            c = c < (u32)LCAP ? c : (u32)LCAP;
            if ((u32)lane < c) {
                u32 pos = base[bin] + lane;
                if (pos < BCAP) binned[bin * BCAP + pos] = buck[bin][lane];
            }
        }
        return;
    }
    int ob = b - NFILLB;
    if (ob < GB) {
        // ---- mm L0: m = x @ W0 (A split bf16, W single bf16; out m16 bf16).
        // W loads batched per kt (32 scalar loads issued together) to avoid
        // load->mfma serialization (the R6 gru lesson applied here too). ----
        int lane = tid & 63;
        int wv = tid >> 6;
        int node0 = ob * 64 + wv * 16;
        if (node0 >= N_NODES) return;
        int c0 = lane & 15, qr = lane >> 4;
        f32x4 acc[4];
#pragma unroll
        for (int nt = 0; nt < 4; ++nt) acc[nt] = (f32x4){0.f, 0.f, 0.f, 0.f};
#pragma unroll
        for (int kt = 0; kt < 2; ++kt) {
            int aoff = (node0 + c0) * 64 + kt * 32 + qr * 8;
            float tmp[8];
#pragma unroll
            for (int j = 0; j < 8; ++j) tmp[j] = x[aoff + j];
            int k0 = kt * 32 + qr * 8;
            float wt[4][8];
#pragma unroll
            for (int nt = 0; nt < 4; ++nt)
#pragma unroll
                for (int j = 0; j < 8; ++j) wt[nt][j] = W[(k0 + j) * 64 + nt * 16 + c0];
            bf16x8 ah, al;
            split8(tmp, ah, al);
#pragma unroll
            for (int nt = 0; nt < 4; ++nt) {
                bf16x8 bb;
                round8(wt[nt], bb);
                acc[nt] = __builtin_amdgcn_mfma_f32_16x16x32_bf16(ah, bb, acc[nt], 0, 0, 0);
                acc[nt] = __builtin_amdgcn_mfma_f32_16x16x32_bf16(al, bb, acc[nt], 0, 0, 0);
            }
        }
#pragma unroll
        for (int nt = 0; nt < 4; ++nt)
#pragma unroll
            for (int r = 0; r < 4; ++r)
                m16[(node0 + qr * 4 + r) * 64 + nt * 16 + c0] = f2bf(acc[nt][r]);
    } else if (ob < GB + 128) {
        // ---- pack GRU B (single bf16) in 16x16x32 fragment order ----
        int idx = (ob - GB) * 256 + tid;
        int j = idx & 7;
        int lane = (idx >> 3) & 63;
        int nt = (idx >> 9) & 15;
        int step = idx >> 13;
        int k = step * 32 + (lane >> 4) * 8 + j;
        int n = nt * 16 + (lane & 15);
        int g = n >> 6, d = n & 63;
        float v;
        if (g == 0)      v = (k < 64) ? wih[d * 64 + k] : whh[d * 64 + (k - 64)];
        else if (g == 1) v = (k < 64) ? wih[(64 + d) * 64 + k] : whh[(64 + d) * 64 + (k - 64)];
        else if (g == 2) v = (k < 64) ? wih[(128 + d) * 64 + k] : 0.f;
        else             v = (k < 64) ? 0.f : whh[(128 + d) * 64 + (k - 64)];
        Bh[idx] = (short)f2bf(v);
    } else if (ob < GB + 144) {
        // ---- pack W layer-1 (Wnext) bf16 fragments for gru DO_MM epilogue.
        // wf[j] == W1[(kt*32+(lane>>4)*8+j)*64 + nt*16+(lane&15)], idx=((kt*4+nt)*64+lane)*8+j.
        // Race-free: consumed only by gru_kernel (later dispatch). ----
        int idx2 = (ob - (GB + 128)) * 256 + tid;  // 0..4095
        int j = idx2 & 7;
        int lane = (idx2 >> 3) & 63;
        int nt = (idx2 >> 9) & 3;
        int kt = idx2 >> 11;
        Wp[idx2] = (short)f2bf(
            W[4096 + (kt * 32 + (lane >> 4) * 8 + j) * 64 + nt * 16 + (lane & 15)]);
    } else {
        int j = tid;
        if (j < 64) {
            bias4[j] = bih[j] + bhh[j];
            bias4[64 + j] = bih[64 + j] + bhh[64 + j];
            bias4[128 + j] = bih[128 + j];
            bias4[192 + j] = bhh[128 + j];
        }
    }
}

// ===== phase 2: block per coarse bin; per-node buckets in LDS, coalesced slab out =====
__global__ __launch_bounds__(256) void bucket_kernel(
        const u32* __restrict__ binned, const u32* __restrict__ binCursor,
        int* __restrict__ deg, u16* __restrict__ srcidx) {
    __shared__ u32 ndeg[256];
    __shared__ __align__(16) u16 nb[256][CAP];  // 32 KB
    int bin = blockIdx.x;
    int tid = threadIdx.x;
    ndeg[tid] = 0;
    __syncthreads();
    int c = (int)binCursor[bin];
    if (c > BCAP) c = BCAP;
    const u32* src = binned + bin * BCAP;
    for (int i = tid; i < c; i += 256) {
        u32 pay = src[i];
        int dl = pay & 255;
        u32 p = atomicAdd(&ndeg[dl], 1u);
        if (p < CAP) nb[dl][p] = (u16)(pay >> 8);
    }
    __syncthreads();
    int node0 = bin * 256;
    int nn = N_NODES - node0;
    if (nn > 256) nn = 256;
    u32x4* dst16 = (u32x4*)(srcidx + (size_t)node0 * CAP);
    const u32x4* src16 = (const u32x4*)nb;
    int tot = nn * 8;
    for (int i = tid; i < tot; i += 256) dst16[i] = src16[i];
    if (tid < nn) {
        u32 d = ndeg[tid];
        deg[node0 + tid] = (int)(d < (u32)CAP ? d : (u32)CAP);
    }
}

// ===== agg: wave per node; half-wave dword gather; OUT: aggf f32 =====
__global__ __launch_bounds__(256) void agg_kernel(const u16* __restrict__ m16,
                                                  const int* __restrict__ deg,
                                                  const u16* __restrict__ srcidx,
                                                  float* __restrict__ aggf) {
    int lane = threadIdx.x & 63;
    int node = blockIdx.x * 4 + (threadIdx.x >> 6);  // grid exact: 50000/4
    int cnt = __builtin_amdgcn_readfirstlane(deg[node]);
    cnt = cnt < CAP ? cnt : CAP;
    int bv = (int)srcidx[node * CAP + lane];
    int half = lane >> 5;
    int l = lane & 31;
    const u32* m32 = (const u32*)m16;
    float a0 = 0.f, a1 = 0.f;
    int k = half;
    for (; k + 6 < cnt; k += 8) {
        int s0 = __shfl(bv, k);
        int s1 = __shfl(bv, k + 2);
        int s2 = __shfl(bv, k + 4);
        int s3 = __shfl(bv, k + 6);
        u32 d0 = m32[s0 * 32 + l];
        u32 d1 = m32[s1 * 32 + l];
        u32 d2 = m32[s2 * 32 + l];
        u32 d3 = m32[s3 * 32 + l];
        a0 += bf2f((u16)d0) + bf2f((u16)d1) + bf2f((u16)d2) + bf2f((u16)d3);
        a1 += bf2f((u16)(d0 >> 16)) + bf2f((u16)(d1 >> 16)) +
              bf2f((u16)(d2 >> 16)) + bf2f((u16)(d3 >> 16));
    }
    for (; k < cnt; k += 2) {
        int s = __shfl(bv, k);
        u32 d = m32[s * 32 + l];
        a0 += bf2f((u16)d);
        a1 += bf2f((u16)(d >> 16));
    }
    a0 += __shfl_xor(a0, 32);
    a1 += __shfl_xor(a1, 32);
    if (half == 0) {  // cols {2l, 2l+1}; coalesced 256B per node
        float2 st;
        st.x = a0;
        st.y = a1;
        ((float2*)aggf)[node * 32 + l] = st;
    }
}

// ===== GRU on 16x16x32 MFMA: one wave = 16 rows. B-fragments PRELOADED in
// register batches of 8 (breaks the measured load->mfma serialization: R6 had
// VGPR=68 => one B-load in flight, ~200cyc exposed per MFMA pair).
// A: row=lane&15, k=(lane>>4)*8+j. C/D: col=lane&15, row=(lane>>4)*4+reg.
// acc[nt] nt=0..15: gates [r(0..3) | z(4..7) | i_n(8..11) | h_n(12..15)] x 16 cols. =====
template <bool DO_MM>
__global__ __launch_bounds__(256) void gru_kernel(
        const float* __restrict__ aggf, const short* __restrict__ Bh,
        const short* __restrict__ Wp, const float* __restrict__ bias4,
        const float* hin,  // x (L0) or h (L1, in-place: waves touch only own rows)
        float* hout, u16* __restrict__ m16) {
    __shared__ __align__(16) float tiles[DO_MM ? 4 * 16 * 65 : 4];
    int tid = threadIdx.x;
    int lane = tid & 63;
    int wv = tid >> 6;
    int wtask = blockIdx.x * 4 + wv;
    if (wtask >= GRUT) return;
    int node0 = wtask * 16;
    int c = lane & 15, q = lane >> 4;  // q in 0..3
    int rowA = node0 + c;
    float* myTile = tiles + (DO_MM ? wv * 16 * 65 : 0);

    f32x4 acc[16];
#pragma unroll
    for (int nt = 0; nt < 16; ++nt) acc[nt] = (f32x4){0.f, 0.f, 0.f, 0.f};

#pragma unroll
    for (int step = 0; step < 4; ++step) {  // logical K: steps 0-1 = agg, 2-3 = h
        const float* src = (step < 2) ? aggf : hin;
        int aoff = rowA * 64 + (step & 1) * 32 + q * 8;
        float tmp[8];
#pragma unroll
        for (int j = 0; j < 8; ++j) tmp[j] = src[aoff + j];
        // batch-issue first 8 B-frag loads; split8 VALU overlaps their latency
        bf16x8 bfr[8];
#pragma unroll
        for (int nt = 0; nt < 8; ++nt)
            bfr[nt] = *(const bf16x8*)(Bh + (step * 16 + nt) * 512 + lane * 8);
        bf16x8 ah, al;
        split8(tmp, ah, al);
#pragma unroll
        for (int nt = 0; nt < 8; ++nt) {
            acc[nt] = __builtin_amdgcn_mfma_f32_16x16x32_bf16(ah, bfr[nt], acc[nt], 0, 0, 0);
            acc[nt] = __builtin_amdgcn_mfma_f32_16x16x32_bf16(al, bfr[nt], acc[nt], 0, 0, 0);
        }
        bf16x8 bfr2[8];
#pragma unroll
        for (int nt = 0; nt < 8; ++nt)
            bfr2[nt] = *(const bf16x8*)(Bh + (step * 16 + 8 + nt) * 512 + lane * 8);
#pragma unroll
        for (int nt = 0; nt < 8; ++nt) {
            acc[8 + nt] =
                __builtin_amdgcn_mfma_f32_16x16x32_bf16(ah, bfr2[nt], acc[8 + nt], 0, 0, 0);
            acc[8 + nt] =
                __builtin_amdgcn_mfma_f32_16x16x32_bf16(al, bfr2[nt], acc[8 + nt], 0, 0, 0);
        }
    }

    // gates: output col j=jt*16+c uses acc {jt, 4+jt, 8+jt, 12+jt} (r, z, i_n, h_n)
#pragma unroll
    for (int reg = 0; reg < 4; ++reg) {
        int R = q * 4 + reg;  // local row 0..15
        int row = node0 + R;
#pragma unroll
        for (int jt = 0; jt < 4; ++jt) {
            int j = jt * 16 + c;
            float rr = sigmoidf_(acc[jt][reg] + bias4[j]);
            float zz = sigmoidf_(acc[4 + jt][reg] + bias4[64 + j]);
            float nn = tanhf_(acc[8 + jt][reg] + bias4[128 + j] +
                              rr * (acc[12 + jt][reg] + bias4[192 + j]));
            float ho = hin[row * 64 + j];
            float v = (1.f - zz) * nn + zz * ho;
            hout[row * 64 + j] = v;
            if (DO_MM) myTile[R * 65 + j] = v;  // <=4-way bank alias on 16 stores
        }
    }

    if (DO_MM) {
        // mm next layer: m16[row] = h[row] @ W1 (bf16 x bf16, W1 pre-packed in Wp)
        f32x4 macc[4];
#pragma unroll
        for (int nt = 0; nt < 4; ++nt) macc[nt] = (f32x4){0.f, 0.f, 0.f, 0.f};
#pragma unroll
        for (int kt = 0; kt < 2; ++kt) {
            int k0 = kt * 32 + q * 8;
            bf16x8 wf[4];
#pragma unroll
            for (int nt = 0; nt < 4; ++nt)
                wf[nt] = *(const bf16x8*)(Wp + ((kt * 4 + nt) * 64 + lane) * 8);
            float tmp[8];
#pragma unroll
            for (int j = 0; j < 8; ++j) tmp[j] = myTile[c * 65 + k0 + j];  // 2-way, free
            bf16x8 aa;
            round8(tmp, aa);
#pragma unroll
            for (int nt = 0; nt < 4; ++nt)
                macc[nt] = __builtin_amdgcn_mfma_f32_16x16x32_bf16(aa, wf[nt], macc[nt], 0, 0, 0);
        }
#pragma unroll
        for (int nt = 0; nt < 4; ++nt)
#pragma unroll
            for (int reg = 0; reg < 4; ++reg)
                m16[(node0 + q * 4 + reg) * 64 + nt * 16 + c] = f2bf(macc[nt][reg]);
    }
}

// ===== fused relu + segment-mean pool + fc1/relu/fc2/log_softmax; block per graph =====
__global__ __launch_bounds__(256) void poolhead_kernel(const float* __restrict__ h,
                                                       const int* __restrict__ batch,
                                                       const float* __restrict__ fc1w,
                                                       const float* __restrict__ fc1b,
                                                       const float* __restrict__ fc2w,
                                                       const float* __restrict__ fc2b,
                                                       float* __restrict__ out) {
    int g = blockIdx.x;
    int tid = threadIdx.x, lane = tid & 63, wv = tid >> 6;
    int lo, hi;
    {
        int a = 0, b = N_NODES;
        while (a < b) { int mid = (a + b) >> 1; if (batch[mid] < g) a = mid + 1; else b = mid; }
        lo = a;
    }
    {
        int a = lo, b = N_NODES;
        while (a < b) { int mid = (a + b) >> 1; if (batch[mid] < g + 1) a = mid + 1; else b = mid; }
        hi = a;
    }
    float acc = 0.f;
    for (int n = lo + wv; n < hi; n += 4) acc += fmaxf(h[n * 64 + lane], 0.f);
    __shared__ float red[4][64];
    __shared__ float pv[64];
    __shared__ float s1[32];
    __shared__ float s2[6];
    red[wv][lane] = acc;
    __syncthreads();
    if (tid < 64)
        pv[tid] = (red[0][tid] + red[1][tid] + red[2][tid] + red[3][tid]) /
                  fmaxf((float)(hi - lo), 1.f);
    __syncthreads();
    if (tid < 32) {
        float a2 = fc1b[tid];
#pragma unroll
        for (int j = 0; j < 64; ++j) a2 = fmaf(pv[j], fc1w[tid * 64 + j], a2);
        s1[tid] = fmaxf(a2, 0.f);
    }
    __syncthreads();
    if (tid < 6) {
        float a2 = fc2b[tid];
#pragma unroll
        for (int j = 0; j < 32; ++j) a2 = fmaf(s1[j], fc2w[tid * 32 + j], a2);
        s2[tid] = a2;
    }
    __syncthreads();
    if (tid == 0) {
        float mx = s2[0];
#pragma unroll
        for (int c = 1; c < 6; ++c) mx = fmaxf(mx, s2[c]);
        float se = 0.f;
#pragma unroll
        for (int c = 0; c < 6; ++c) se += __expf(s2[c] - mx);
        float lse = mx + __logf(se);
#pragma unroll
        for (int c = 0; c < 6; ++c) out[g * 6 + c] = s2[c] - lse;
    }
}

extern "C" void kernel_launch(void* const* d_in, const int* in_sizes, int n_in,
                              void* d_out, int out_size, void* d_ws, size_t ws_size,
                              hipStream_t stream) {
    const float* x    = (const float*)d_in[0];
    const int* ei     = (const int*)d_in[1];
    const int* batch  = (const int*)d_in[2];
    const float* W    = (const float*)d_in[3];
    const float* wih  = (const float*)d_in[4];
    const float* whh  = (const float*)d_in[5];
    const float* bih  = (const float*)d_in[6];
    const float* bhh  = (const float*)d_in[7];
    const float* fc1w = (const float*)d_in[8];
    const float* fc1b = (const float*)d_in[9];
    const float* fc2w = (const float*)d_in[10];
    const float* fc2b = (const float*)d_in[11];
    float* out = (float*)d_out;

    // ---- workspace layout ----
    float* h       = (float*)d_ws;               // 12.8 MB
    float* bias4   = h + N_NODES * D1;           // 256 f
    int* deg       = (int*)(bias4 + 256);        // N_NODES
    u16* srcidx    = (u16*)(deg + N_NODES);      // 6.4 MB
    size_t soff = ((size_t)(srcidx + N_NODES * CAP) + 15) & ~(size_t)15;
    u16* m16    = (u16*)soff;                    // 6.4 MB
    float* aggf = (float*)(m16 + N_NODES * D1);  // 12.8 MB f32 agg
    short* Bh   = (short*)(aggf + N_NODES * D1); // 64 KB
    short* Wp   = Bh + 32768;                    // 8 KB packed W1 frags
    u32* binCursor = (u32*)(Wp + 4096);          // NBINS u32
    // binned runs (4.8 MB) alias the start of aggf: consumed by bucket_kernel,
    // aggf first written by agg_kernel strictly after (kernel boundary).
    u32* binned = (u32*)aggf;

    hipMemsetAsync(binCursor, 0, NBINS * sizeof(u32), stream);
    // phase 1 (196 fill blocks, start immediately) + mm L0 + Bh/Wp pack + bias
    fused_head_kernel<<<FH_BLOCKS, 256, 0, stream>>>(
        ei, binned, binCursor, x, W, wih, whh, bih, bhh, Bh, Wp, bias4, m16);
    // phase 2: per-bin bucket build, fully coalesced srcidx/deg writes
    bucket_kernel<<<NBINS, 256, 0, stream>>>(binned, binCursor, deg, srcidx);

    // layer 0: agg -> gru (+ fused mm of layer 1 into m16)
    agg_kernel<<<N_NODES / 4, 256, 0, stream>>>(m16, deg, srcidx, aggf);
    gru_kernel<true><<<GB, 256, 0, stream>>>(aggf, Bh, Wp, bias4, x, h, m16);
    // layer 1: agg -> gru (in-place h)
    agg_kernel<<<N_NODES / 4, 256, 0, stream>>>(m16, deg, srcidx, aggf);
    gru_kernel<false><<<GB, 256, 0, stream>>>(aggf, Bh, Wp, bias4, h, h, nullptr);

    poolhead_kernel<<<N_GRAPHS, 256, 0, stream>>>(h, batch, fc1w, fc1b, fc2w, fc2b, out);
}

// Round 8
// 223.570 us; speedup vs baseline: 1.2875x; 1.0622x over previous
//
#include <hip/hip_runtime.h>

#define N_NODES 50000
#define N_EDGES 800000
#define D1 64
#define D2 32
#define N_CLASSES 6
#define N_GRAPHS 128
#define CAP 64       // per-node src bucket capacity == wave size; deg max ~45 << 64
#define GB 782       // ceil(50000/64) for 16x16 mm tiles (mm L0 in fused kernel)
#define GRUT 3125    // 50000/16: per-wave gru tasks (16 rows each, exact)

// ---- two-level binned fill ----
#define NBINS 196    // ceil(50000/256): coarse bin = dst>>8 (256 nodes per bin)
#define BCAP 6144    // per-bin global run capacity (mean 4081, >16 sigma headroom)
#define EPB 4096     // edges per phase-1 fill block
#define NFILLB 196   // ceil(800000/4096)
#define LCAP 48      // per-(block,bin) LDS capacity (mean 20.9, ~6 sigma; overflow -> direct)
#define FH_BLOCKS (NFILLB + GB + 128 + 16 + 1)  // fill + mm + Bh pack + Wp pack + bias

typedef unsigned short u16;
typedef unsigned int u32;
typedef __attribute__((ext_vector_type(4))) int i32x4;
typedef __attribute__((ext_vector_type(4))) unsigned int u32x4;
typedef __attribute__((ext_vector_type(8))) short bf16x8;
typedef __attribute__((ext_vector_type(4))) float f32x4;

__device__ __forceinline__ float bf2f(u16 b) {
    u32 u = ((u32)b) << 16;
    float f;
    __builtin_memcpy(&f, &u, 4);
    return f;
}
__device__ __forceinline__ u16 f2bf(float f) {
    u32 u;
    __builtin_memcpy(&u, &f, 4);
    u32 r = (u + 0x7fffu + ((u >> 16) & 1u)) >> 16;
    return (u16)r;
}
__device__ __forceinline__ void split8(const float* v, bf16x8& hi, bf16x8& lo) {
#pragma unroll
    for (int j = 0; j < 8; ++j) {
        u16 h = f2bf(v[j]);
        hi[j] = (short)h;
        lo[j] = (short)f2bf(v[j] - bf2f(h));
    }
}
__device__ __forceinline__ void round8(const float* v, bf16x8& b) {
#pragma unroll
    for (int j = 0; j < 8; ++j) b[j] = (short)f2bf(v[j]);
}
__device__ __forceinline__ float sigmoidf_(float x) {
    return 1.0f / (1.0f + __expf(-x));
}
__device__ __forceinline__ float tanhf_(float x) {
    return 1.0f - 2.0f / (__expf(2.0f * x) + 1.0f);
}

// ===== fused: phase-1 binned edge scatter + pack + mm L0 (unchanged, known-good) =====
__global__ __launch_bounds__(256) void fused_head_kernel(
        const int* __restrict__ ei, u32* __restrict__ binned, u32* __restrict__ binCursor,
        const float* __restrict__ x, const float* __restrict__ W,
        const float* __restrict__ wih, const float* __restrict__ whh,
        const float* __restrict__ bih, const float* __restrict__ bhh,
        short* __restrict__ Bh, short* __restrict__ Wp, float* __restrict__ bias4,
        u16* __restrict__ m16) {
    __shared__ u32 cnt[NBINS];
    __shared__ u32 base[NBINS];
    __shared__ u32 buck[NBINS][LCAP];  // 37.6 KB
    int b = blockIdx.x;
    int tid = threadIdx.x;
    if (b < NFILLB) {
        for (int i = tid; i < NBINS; i += 256) cnt[i] = 0;
        __syncthreads();
        int e0 = b * EPB;
        int nq = (min(EPB, N_EDGES - e0)) >> 2;
        const i32x4* s4 = (const i32x4*)ei + (e0 >> 2);
        const i32x4* d4 = (const i32x4*)(ei + N_EDGES) + (e0 >> 2);
#pragma unroll
        for (int ch = 0; ch < 4; ++ch) {
            int i = ch * 256 + tid;
            if (i < nq) {
                i32x4 ss = s4[i];
                i32x4 dd = d4[i];
#pragma unroll
                for (int j = 0; j < 4; ++j) {
                    int s = ss[j];
                    int d = dd[j];
                    int bin = d >> 8;
                    u32 pay = ((u32)s << 8) | (u32)(d & 255);
                    u32 p = atomicAdd(&cnt[bin], 1u);
                    if (p < LCAP) buck[bin][p] = pay;
                    else {
                        u32 q = atomicAdd(&binCursor[bin], 1u);
                        if (q < BCAP) binned[bin * BCAP + q] = pay;
                    }
                }
            }
        }
        __syncthreads();
        int lane = tid & 63, wv = tid >> 6;
        if (lane < 49) {
            int bin = wv * 49 + lane;
            u32 c = cnt[bin];
            c = c < (u32)LCAP ? c : (u32)LCAP;
            base[bin] = atomicAdd(&binCursor[bin], c);
        }
        __syncthreads();
        for (int idx = 0; idx < 49; ++idx) {
            int bin = wv * 49 + idx;
            u32 c = cnt[bin];
            c = c < (u32)LCAP ? c : (u32)LCAP;
            if ((u32)lane < c) {
                u32 pos = base[bin] + lane;
                if (pos < BCAP) binned[bin * BCAP + pos] = buck[bin][lane];
            }
        }
        return;
    }
    int ob = b - NFILLB;
    if (ob < GB) {
        // ---- mm L0: m = x @ W0 (A split bf16, W single bf16; W loads batched) ----
        int lane = tid & 63;
        int wv = tid >> 6;
        int node0 = ob * 64 + wv * 16;
        if (node0 >= N_NODES) return;
        int c0 = lane & 15, qr = lane >> 4;
        f32x4 acc[4];
#pragma unroll
        for (int nt = 0; nt < 4; ++nt) acc[nt] = (f32x4){0.f, 0.f, 0.f, 0.f};
#pragma unroll
        for (int kt = 0; kt < 2; ++kt) {
            int aoff = (node0 + c0) * 64 + kt * 32 + qr * 8;
            float tmp[8];
#pragma unroll
            for (int j = 0; j < 8; ++j) tmp[j] = x[aoff + j];
            int k0 = kt * 32 + qr * 8;
            float wt[4][8];
#pragma unroll
            for (int nt = 0; nt < 4; ++nt)
#pragma unroll
                for (int j = 0; j < 8; ++j) wt[nt][j] = W[(k0 + j) * 64 + nt * 16 + c0];
            bf16x8 ah, al;
            split8(tmp, ah, al);
#pragma unroll
            for (int nt = 0; nt < 4; ++nt) {
                bf16x8 bb;
                round8(wt[nt], bb);
                acc[nt] = __builtin_amdgcn_mfma_f32_16x16x32_bf16(ah, bb, acc[nt], 0, 0, 0);
                acc[nt] = __builtin_amdgcn_mfma_f32_16x16x32_bf16(al, bb, acc[nt], 0, 0, 0);
            }
        }
#pragma unroll
        for (int nt = 0; nt < 4; ++nt)
#pragma unroll
            for (int r = 0; r < 4; ++r)
                m16[(node0 + qr * 4 + r) * 64 + nt * 16 + c0] = f2bf(acc[nt][r]);
    } else if (ob < GB + 128) {
        // ---- pack GRU B (single bf16) in 16x16x32 fragment order ----
        int idx = (ob - GB) * 256 + tid;
        int j = idx & 7;
        int lane = (idx >> 3) & 63;
        int nt = (idx >> 9) & 15;
        int step = idx >> 13;
        int k = step * 32 + (lane >> 4) * 8 + j;
        int n = nt * 16 + (lane & 15);
        int g = n >> 6, d = n & 63;
        float v;
        if (g == 0)      v = (k < 64) ? wih[d * 64 + k] : whh[d * 64 + (k - 64)];
        else if (g == 1) v = (k < 64) ? wih[(64 + d) * 64 + k] : whh[(64 + d) * 64 + (k - 64)];
        else if (g == 2) v = (k < 64) ? wih[(128 + d) * 64 + k] : 0.f;
        else             v = (k < 64) ? 0.f : whh[(128 + d) * 64 + (k - 64)];
        Bh[idx] = (short)f2bf(v);
    } else if (ob < GB + 144) {
        // ---- pack W layer-1 bf16 fragments for gru DO_MM epilogue ----
        int idx2 = (ob - (GB + 128)) * 256 + tid;  // 0..4095
        int j = idx2 & 7;
        int lane = (idx2 >> 3) & 63;
        int nt = (idx2 >> 9) & 3;
        int kt = idx2 >> 11;
        Wp[idx2] = (short)f2bf(
            W[4096 + (kt * 32 + (lane >> 4) * 8 + j) * 64 + nt * 16 + (lane & 15)]);
    } else {
        int j = tid;
        if (j < 64) {
            bias4[j] = bih[j] + bhh[j];
            bias4[64 + j] = bih[64 + j] + bhh[64 + j];
            bias4[128 + j] = bih[128 + j];
            bias4[192 + j] = bhh[128 + j];
        }
    }
}

// ===== phase 2: block per coarse bin; per-node buckets in LDS, coalesced slab out =====
__global__ __launch_bounds__(256) void bucket_kernel(
        const u32* __restrict__ binned, const u32* __restrict__ binCursor,
        int* __restrict__ deg, u16* __restrict__ srcidx) {
    __shared__ u32 ndeg[256];
    __shared__ __align__(16) u16 nb[256][CAP];  // 32 KB
    int bin = blockIdx.x;
    int tid = threadIdx.x;
    ndeg[tid] = 0;
    __syncthreads();
    int c = (int)binCursor[bin];
    if (c > BCAP) c = BCAP;
    const u32* src = binned + bin * BCAP;
    for (int i = tid; i < c; i += 256) {
        u32 pay = src[i];
        int dl = pay & 255;
        u32 p = atomicAdd(&ndeg[dl], 1u);
        if (p < CAP) nb[dl][p] = (u16)(pay >> 8);
    }
    __syncthreads();
    int node0 = bin * 256;
    int nn = N_NODES - node0;
    if (nn > 256) nn = 256;
    u32x4* dst16 = (u32x4*)(srcidx + (size_t)node0 * CAP);
    const u32x4* src16 = (const u32x4*)nb;
    int tot = nn * 8;
    for (int i = tid; i < tot; i += 256) dst16[i] = src16[i];
    if (tid < nn) {
        u32 d = ndeg[tid];
        deg[node0 + tid] = (int)(d < (u32)CAP ? d : (u32)CAP);
    }
}

// ===== agg: wave per node; half-wave dword gather; OUT: aggf f32 =====
__global__ __launch_bounds__(256) void agg_kernel(const u16* __restrict__ m16,
                                                  const int* __restrict__ deg,
                                                  const u16* __restrict__ srcidx,
                                                  float* __restrict__ aggf) {
    int lane = threadIdx.x & 63;
    int node = blockIdx.x * 4 + (threadIdx.x >> 6);  // grid exact: 50000/4
    int cnt = __builtin_amdgcn_readfirstlane(deg[node]);
    cnt = cnt < CAP ? cnt : CAP;
    int bv = (int)srcidx[node * CAP + lane];
    int half = lane >> 5;
    int l = lane & 31;
    const u32* m32 = (const u32*)m16;
    float a0 = 0.f, a1 = 0.f;
    int k = half;
    for (; k + 6 < cnt; k += 8) {
        int s0 = __shfl(bv, k);
        int s1 = __shfl(bv, k + 2);
        int s2 = __shfl(bv, k + 4);
        int s3 = __shfl(bv, k + 6);
        u32 d0 = m32[s0 * 32 + l];
        u32 d1 = m32[s1 * 32 + l];
        u32 d2 = m32[s2 * 32 + l];
        u32 d3 = m32[s3 * 32 + l];
        a0 += bf2f((u16)d0) + bf2f((u16)d1) + bf2f((u16)d2) + bf2f((u16)d3);
        a1 += bf2f((u16)(d0 >> 16)) + bf2f((u16)(d1 >> 16)) +
              bf2f((u16)(d2 >> 16)) + bf2f((u16)(d3 >> 16));
    }
    for (; k < cnt; k += 2) {
        int s = __shfl(bv, k);
        u32 d = m32[s * 32 + l];
        a0 += bf2f((u16)d);
        a1 += bf2f((u16)(d >> 16));
    }
    a0 += __shfl_xor(a0, 32);
    a1 += __shfl_xor(a1, 32);
    if (half == 0) {  // cols {2l, 2l+1}; coalesced 256B per node
        float2 st;
        st.x = a0;
        st.y = a1;
        ((float2*)aggf)[node * 32 + l] = st;
    }
}

// ===== GRU on 16x16x32 MFMA: wave = 16 rows. A-data (4 steps x 8 f32) prefetched
// at wave start (all HBM-latency loads in flight before first MFMA); B-fragments
// batch-loaded by 8 (R7 win). DO_MM (layer 0): writes h + fused mm into m16.
// !DO_MM (layer 1, LAST): NO h write — fused relu+segment-sum pooling into gsum
// (wave reduces its 16 rows per column: 4 adds + 2 shfl_xor + ONE atomicAdd/lane
// when the wave's nodes share a graph; guarded per-row atomics at boundaries). =====
template <bool DO_MM>
__global__ __launch_bounds__(256) void gru_kernel(
        const float* __restrict__ aggf, const short* __restrict__ Bh,
        const short* __restrict__ Wp, const float* __restrict__ bias4,
        const float* hin,  // x (L0) or h (L1)
        float* hout, u16* __restrict__ m16,
        const int* __restrict__ batch, float* __restrict__ gsum) {
    __shared__ __align__(16) float tiles[DO_MM ? 4 * 16 * 65 : 4];
    int tid = threadIdx.x;
    int lane = tid & 63;
    int wv = tid >> 6;
    int wtask = blockIdx.x * 4 + wv;
    if (wtask >= GRUT) return;
    int node0 = wtask * 16;
    int c = lane & 15, q = lane >> 4;  // q in 0..3
    int rowA = node0 + c;
    float* myTile = tiles + (DO_MM ? wv * 16 * 65 : 0);

    // ---- prefetch ALL A-data: 4 steps x 8 f32 (batched; latency hidden) ----
    const float* aggrow = aggf + rowA * 64 + q * 8;
    const float* hinrow = hin + rowA * 64 + q * 8;
    float av0[8], av1[8], hv0[8], hv1[8];
#pragma unroll
    for (int j = 0; j < 8; ++j) av0[j] = aggrow[j];
#pragma unroll
    for (int j = 0; j < 8; ++j) av1[j] = aggrow[32 + j];
#pragma unroll
    for (int j = 0; j < 8; ++j) hv0[j] = hinrow[j];
#pragma unroll
    for (int j = 0; j < 8; ++j) hv1[j] = hinrow[32 + j];

    f32x4 acc[16];
#pragma unroll
    for (int nt = 0; nt < 16; ++nt) acc[nt] = (f32x4){0.f, 0.f, 0.f, 0.f};

#pragma unroll
    for (int step = 0; step < 4; ++step) {  // logical K: steps 0-1 = agg, 2-3 = h
        const float* tmp = (step == 0) ? av0 : (step == 1) ? av1 : (step == 2) ? hv0 : hv1;
        bf16x8 bfr[8];
#pragma unroll
        for (int nt = 0; nt < 8; ++nt)
            bfr[nt] = *(const bf16x8*)(Bh + (step * 16 + nt) * 512 + lane * 8);
        bf16x8 ah, al;
        split8(tmp, ah, al);
#pragma unroll
        for (int nt = 0; nt < 8; ++nt) {
            acc[nt] = __builtin_amdgcn_mfma_f32_16x16x32_bf16(ah, bfr[nt], acc[nt], 0, 0, 0);
            acc[nt] = __builtin_amdgcn_mfma_f32_16x16x32_bf16(al, bfr[nt], acc[nt], 0, 0, 0);
        }
        bf16x8 bfr2[8];
#pragma unroll
        for (int nt = 0; nt < 8; ++nt)
            bfr2[nt] = *(const bf16x8*)(Bh + (step * 16 + 8 + nt) * 512 + lane * 8);
#pragma unroll
        for (int nt = 0; nt < 8; ++nt) {
            acc[8 + nt] =
                __builtin_amdgcn_mfma_f32_16x16x32_bf16(ah, bfr2[nt], acc[8 + nt], 0, 0, 0);
            acc[8 + nt] =
                __builtin_amdgcn_mfma_f32_16x16x32_bf16(al, bfr2[nt], acc[8 + nt], 0, 0, 0);
        }
    }

    // gates: output col j=jt*16+c uses acc {jt, 4+jt, 8+jt, 12+jt} (r, z, i_n, h_n)
    float psum[4] = {0.f, 0.f, 0.f, 0.f};
    int b0 = 0;
    bool uniform = false;
    if (!DO_MM) {
        b0 = batch[node0];
        uniform = (b0 == batch[node0 + 15]);
    }
#pragma unroll
    for (int reg = 0; reg < 4; ++reg) {
        int R = q * 4 + reg;  // local row 0..15
        int row = node0 + R;
#pragma unroll
        for (int jt = 0; jt < 4; ++jt) {
            int j = jt * 16 + c;
            float rr = sigmoidf_(acc[jt][reg] + bias4[j]);
            float zz = sigmoidf_(acc[4 + jt][reg] + bias4[64 + j]);
            float nn = tanhf_(acc[8 + jt][reg] + bias4[128 + j] +
                              rr * (acc[12 + jt][reg] + bias4[192 + j]));
            float ho = hin[row * 64 + j];
            float v = (1.f - zz) * nn + zz * ho;
            if (DO_MM) {
                hout[row * 64 + j] = v;
                myTile[R * 65 + j] = v;  // <=4-way bank alias on 16 stores
            } else {
                float rv = fmaxf(v, 0.f);
                if (uniform) psum[jt] += rv;
                else atomicAdd(&gsum[batch[row] * 64 + j], rv);
            }
        }
    }

    if (!DO_MM) {
        if (uniform) {
#pragma unroll
            for (int jt = 0; jt < 4; ++jt) {
                psum[jt] += __shfl_xor(psum[jt], 16);
                psum[jt] += __shfl_xor(psum[jt], 32);
            }
            // lane (q,c) emits column q*16+c (covers all 64 cols exactly once)
            float emit = q == 0 ? psum[0] : q == 1 ? psum[1] : q == 2 ? psum[2] : psum[3];
            atomicAdd(&gsum[b0 * 64 + q * 16 + c], emit);
        }
        return;
    }

    if (DO_MM) {
        // mm next layer: m16[row] = h[row] @ W1 (bf16 x bf16, W1 pre-packed in Wp)
        f32x4 macc[4];
#pragma unroll
        for (int nt = 0; nt < 4; ++nt) macc[nt] = (f32x4){0.f, 0.f, 0.f, 0.f};
#pragma unroll
        for (int kt = 0; kt < 2; ++kt) {
            int k0 = kt * 32 + q * 8;
            bf16x8 wf[4];
#pragma unroll
            for (int nt = 0; nt < 4; ++nt)
                wf[nt] = *(const bf16x8*)(Wp + ((kt * 4 + nt) * 64 + lane) * 8);
            float tmp[8];
#pragma unroll
            for (int j = 0; j < 8; ++j) tmp[j] = myTile[c * 65 + k0 + j];  // 2-way, free
            bf16x8 aa;
            round8(tmp, aa);
#pragma unroll
            for (int nt = 0; nt < 4; ++nt)
                macc[nt] = __builtin_amdgcn_mfma_f32_16x16x32_bf16(aa, wf[nt], macc[nt], 0, 0, 0);
        }
#pragma unroll
        for (int nt = 0; nt < 4; ++nt)
#pragma unroll
            for (int reg = 0; reg < 4; ++reg)
                m16[(node0 + q * 4 + reg) * 64 + nt * 16 + c] = f2bf(macc[nt][reg]);
    }
}

// ===== head: block per graph; mean from gsum (32KB) + fc1/relu/fc2/log_softmax =====
__global__ __launch_bounds__(64) void head_kernel(const float* __restrict__ gsum,
                                                  const int* __restrict__ batch,
                                                  const float* __restrict__ fc1w,
                                                  const float* __restrict__ fc1b,
                                                  const float* __restrict__ fc2w,
                                                  const float* __restrict__ fc2b,
                                                  float* __restrict__ out) {
    int g = blockIdx.x;
    int tid = threadIdx.x;
    int lo, hi;
    {
        int a = 0, b = N_NODES;
        while (a < b) { int mid = (a + b) >> 1; if (batch[mid] < g) a = mid + 1; else b = mid; }
        lo = a;
    }
    {
        int a = lo, b = N_NODES;
        while (a < b) { int mid = (a + b) >> 1; if (batch[mid] < g + 1) a = mid + 1; else b = mid; }
        hi = a;
    }
    __shared__ float pv[64];
    __shared__ float s1[32];
    __shared__ float s2[6];
    pv[tid] = gsum[g * 64 + tid] / fmaxf((float)(hi - lo), 1.f);
    __syncthreads();
    if (tid < 32) {
        float a2 = fc1b[tid];
#pragma unroll
        for (int j = 0; j < 64; ++j) a2 = fmaf(pv[j], fc1w[tid * 64 + j], a2);
        s1[tid] = fmaxf(a2, 0.f);
    }
    __syncthreads();
    if (tid < 6) {
        float a2 = fc2b[tid];
#pragma unroll
        for (int j = 0; j < 32; ++j) a2 = fmaf(s1[j], fc2w[tid * 32 + j], a2);
        s2[tid] = a2;
    }
    __syncthreads();
    if (tid == 0) {
        float mx = s2[0];
#pragma unroll
        for (int c = 1; c < 6; ++c) mx = fmaxf(mx, s2[c]);
        float se = 0.f;
#pragma unroll
        for (int c = 0; c < 6; ++c) se += __expf(s2[c] - mx);
        float lse = mx + __logf(se);
#pragma unroll
        for (int c = 0; c < 6; ++c) out[g * 6 + c] = s2[c] - lse;
    }
}

extern "C" void kernel_launch(void* const* d_in, const int* in_sizes, int n_in,
                              void* d_out, int out_size, void* d_ws, size_t ws_size,
                              hipStream_t stream) {
    const float* x    = (const float*)d_in[0];
    const int* ei     = (const int*)d_in[1];
    const int* batch  = (const int*)d_in[2];
    const float* W    = (const float*)d_in[3];
    const float* wih  = (const float*)d_in[4];
    const float* whh  = (const float*)d_in[5];
    const float* bih  = (const float*)d_in[6];
    const float* bhh  = (const float*)d_in[7];
    const float* fc1w = (const float*)d_in[8];
    const float* fc1b = (const float*)d_in[9];
    const float* fc2w = (const float*)d_in[10];
    const float* fc2b = (const float*)d_in[11];
    float* out = (float*)d_out;

    // ---- workspace layout ----
    float* h       = (float*)d_ws;               // 12.8 MB
    float* bias4   = h + N_NODES * D1;           // 256 f
    int* deg       = (int*)(bias4 + 256);        // N_NODES
    u16* srcidx    = (u16*)(deg + N_NODES);      // 6.4 MB
    size_t soff = ((size_t)(srcidx + N_NODES * CAP) + 15) & ~(size_t)15;
    u16* m16    = (u16*)soff;                    // 6.4 MB
    float* aggf = (float*)(m16 + N_NODES * D1);  // 12.8 MB f32 agg
    short* Bh   = (short*)(aggf + N_NODES * D1); // 64 KB
    short* Wp   = Bh + 32768;                    // 8 KB packed W1 frags
    u32* binCursor = (u32*)(Wp + 4096);          // NBINS u32
    float* gsum = (float*)(binCursor + NBINS);   // 32 KB pooled relu-sums (memset w/ cursor)
    // binned runs (4.8 MB) alias the start of aggf: consumed by bucket_kernel,
    // aggf first written by agg_kernel strictly after (kernel boundary).
    u32* binned = (u32*)aggf;

    // one memset covers binCursor (784 B) + gsum (32 KB), contiguous
    hipMemsetAsync(binCursor, 0, NBINS * sizeof(u32) + N_GRAPHS * D1 * sizeof(float), stream);
    // phase 1 (196 fill blocks, start immediately) + mm L0 + Bh/Wp pack + bias
    fused_head_kernel<<<FH_BLOCKS, 256, 0, stream>>>(
        ei, binned, binCursor, x, W, wih, whh, bih, bhh, Bh, Wp, bias4, m16);
    // phase 2: per-bin bucket build, fully coalesced srcidx/deg writes
    bucket_kernel<<<NBINS, 256, 0, stream>>>(binned, binCursor, deg, srcidx);

    // layer 0: agg -> gru (+ fused mm of layer 1 into m16)
    agg_kernel<<<N_NODES / 4, 256, 0, stream>>>(m16, deg, srcidx, aggf);
    gru_kernel<true><<<GB, 256, 0, stream>>>(aggf, Bh, Wp, bias4, x, h, m16, batch, gsum);
    // layer 1: agg -> gru (LAST: fused relu+pool into gsum, no h write)
    agg_kernel<<<N_NODES / 4, 256, 0, stream>>>(m16, deg, srcidx, aggf);
    gru_kernel<false><<<GB, 256, 0, stream>>>(aggf, Bh, Wp, bias4, h, nullptr, nullptr,
                                              batch, gsum);

    head_kernel<<<N_GRAPHS, 64, 0, stream>>>(gsum, batch, fc1w, fc1b, fc2w, fc2b, out);
}

// Round 9
// 200.530 us; speedup vs baseline: 1.4354x; 1.1149x over previous
//
#include <hip/hip_runtime.h>

#define N_NODES 50000
#define N_EDGES 800000
#define D1 64
#define D2 32
#define N_CLASSES 6
#define N_GRAPHS 128
#define CAP 64       // per-node src bucket capacity == wave size; deg max ~45 << 64
#define GB 782       // ceil(50000/64) for 16x16 mm tiles (mm L0 in fused kernel)
#define GRUT 3125    // 50000/16: per-wave gru tasks (16 rows each, exact)

// ---- two-level binned fill ----
#define NBINS 196    // ceil(50000/256): coarse bin = dst>>8 (256 nodes per bin)
#define BCAP 6144    // per-bin global run capacity (mean 4081, >16 sigma headroom)
#define EPB 4096     // edges per phase-1 fill block
#define NFILLB 196   // ceil(800000/4096)
#define LCAP 48      // per-(block,bin) LDS capacity (mean 20.9, ~6 sigma; overflow -> direct)
#define FH_BLOCKS (NFILLB + GB + 128 + 16 + 1)  // fill + mm + Bh pack + Wp pack + bias

typedef unsigned short u16;
typedef unsigned int u32;
typedef __attribute__((ext_vector_type(4))) int i32x4;
typedef __attribute__((ext_vector_type(4))) unsigned int u32x4;
typedef __attribute__((ext_vector_type(8))) short bf16x8;
typedef __attribute__((ext_vector_type(4))) float f32x4;

__device__ __forceinline__ float bf2f(u16 b) {
    u32 u = ((u32)b) << 16;
    float f;
    __builtin_memcpy(&f, &u, 4);
    return f;
}
__device__ __forceinline__ u16 f2bf(float f) {
    u32 u;
    __builtin_memcpy(&u, &f, 4);
    u32 r = (u + 0x7fffu + ((u >> 16) & 1u)) >> 16;
    return (u16)r;
}
__device__ __forceinline__ void split8(const float* v, bf16x8& hi, bf16x8& lo) {
#pragma unroll
    for (int j = 0; j < 8; ++j) {
        u16 h = f2bf(v[j]);
        hi[j] = (short)h;
        lo[j] = (short)f2bf(v[j] - bf2f(h));
    }
}
__device__ __forceinline__ void round8(const float* v, bf16x8& b) {
#pragma unroll
    for (int j = 0; j < 8; ++j) b[j] = (short)f2bf(v[j]);
}
__device__ __forceinline__ float sigmoidf_(float x) {
    return 1.0f / (1.0f + __expf(-x));
}
__device__ __forceinline__ float tanhf_(float x) {
    return 1.0f - 2.0f / (__expf(2.0f * x) + 1.0f);
}

// ===== fused: phase-1 binned edge scatter + pack + mm L0 (unchanged, known-good) =====
__global__ __launch_bounds__(256) void fused_head_kernel(
        const int* __restrict__ ei, u32* __restrict__ binned, u32* __restrict__ binCursor,
        const float* __restrict__ x, const float* __restrict__ W,
        const float* __restrict__ wih, const float* __restrict__ whh,
        const float* __restrict__ bih, const float* __restrict__ bhh,
        short* __restrict__ Bh, short* __restrict__ Wp, float* __restrict__ bias4,
        u16* __restrict__ m16) {
    __shared__ u32 cnt[NBINS];
    __shared__ u32 base[NBINS];
    __shared__ u32 buck[NBINS][LCAP];  // 37.6 KB
    int b = blockIdx.x;
    int tid = threadIdx.x;
    if (b < NFILLB) {
        for (int i = tid; i < NBINS; i += 256) cnt[i] = 0;
        __syncthreads();
        int e0 = b * EPB;
        int nq = (min(EPB, N_EDGES - e0)) >> 2;
        const i32x4* s4 = (const i32x4*)ei + (e0 >> 2);
        const i32x4* d4 = (const i32x4*)(ei + N_EDGES) + (e0 >> 2);
#pragma unroll
        for (int ch = 0; ch < 4; ++ch) {
            int i = ch * 256 + tid;
            if (i < nq) {
                i32x4 ss = s4[i];
                i32x4 dd = d4[i];
#pragma unroll
                for (int j = 0; j < 4; ++j) {
                    int s = ss[j];
                    int d = dd[j];
                    int bin = d >> 8;
                    u32 pay = ((u32)s << 8) | (u32)(d & 255);
                    u32 p = atomicAdd(&cnt[bin], 1u);
                    if (p < LCAP) buck[bin][p] = pay;
                    else {
                        u32 q = atomicAdd(&binCursor[bin], 1u);
                        if (q < BCAP) binned[bin * BCAP + q] = pay;
                    }
                }
            }
        }
        __syncthreads();
        int lane = tid & 63, wv = tid >> 6;
        if (lane < 49) {
            int bin = wv * 49 + lane;
            u32 c = cnt[bin];
            c = c < (u32)LCAP ? c : (u32)LCAP;
            base[bin] = atomicAdd(&binCursor[bin], c);
        }
        __syncthreads();
        for (int idx = 0; idx < 49; ++idx) {
            int bin = wv * 49 + idx;
            u32 c = cnt[bin];
            c = c < (u32)LCAP ? c : (u32)LCAP;
            if ((u32)lane < c) {
                u32 pos = base[bin] + lane;
                if (pos < BCAP) binned[bin * BCAP + pos] = buck[bin][lane];
            }
        }
        return;
    }
    int ob = b - NFILLB;
    if (ob < GB) {
        // ---- mm L0: m = x @ W0 (A split bf16, W single bf16; W loads batched) ----
        int lane = tid & 63;
        int wv = tid >> 6;
        int node0 = ob * 64 + wv * 16;
        if (node0 >= N_NODES) return;
        int c0 = lane & 15, qr = lane >> 4;
        f32x4 acc[4];
#pragma unroll
        for (int nt = 0; nt < 4; ++nt) acc[nt] = (f32x4){0.f, 0.f, 0.f, 0.f};
#pragma unroll
        for (int kt = 0; kt < 2; ++kt) {
            int aoff = (node0 + c0) * 64 + kt * 32 + qr * 8;
            float tmp[8];
#pragma unroll
            for (int j = 0; j < 8; ++j) tmp[j] = x[aoff + j];
            int k0 = kt * 32 + qr * 8;
            float wt[4][8];
#pragma unroll
            for (int nt = 0; nt < 4; ++nt)
#pragma unroll
                for (int j = 0; j < 8; ++j) wt[nt][j] = W[(k0 + j) * 64 + nt * 16 + c0];
            bf16x8 ah, al;
            split8(tmp, ah, al);
#pragma unroll
            for (int nt = 0; nt < 4; ++nt) {
                bf16x8 bb;
                round8(wt[nt], bb);
                acc[nt] = __builtin_amdgcn_mfma_f32_16x16x32_bf16(ah, bb, acc[nt], 0, 0, 0);
                acc[nt] = __builtin_amdgcn_mfma_f32_16x16x32_bf16(al, bb, acc[nt], 0, 0, 0);
            }
        }
#pragma unroll
        for (int nt = 0; nt < 4; ++nt)
#pragma unroll
            for (int r = 0; r < 4; ++r)
                m16[(node0 + qr * 4 + r) * 64 + nt * 16 + c0] = f2bf(acc[nt][r]);
    } else if (ob < GB + 128) {
        // ---- pack GRU B (single bf16) in 16x16x32 fragment order ----
        int idx = (ob - GB) * 256 + tid;
        int j = idx & 7;
        int lane = (idx >> 3) & 63;
        int nt = (idx >> 9) & 15;
        int step = idx >> 13;
        int k = step * 32 + (lane >> 4) * 8 + j;
        int n = nt * 16 + (lane & 15);
        int g = n >> 6, d = n & 63;
        float v;
        if (g == 0)      v = (k < 64) ? wih[d * 64 + k] : whh[d * 64 + (k - 64)];
        else if (g == 1) v = (k < 64) ? wih[(64 + d) * 64 + k] : whh[(64 + d) * 64 + (k - 64)];
        else if (g == 2) v = (k < 64) ? wih[(128 + d) * 64 + k] : 0.f;
        else             v = (k < 64) ? 0.f : whh[(128 + d) * 64 + (k - 64)];
        Bh[idx] = (short)f2bf(v);
    } else if (ob < GB + 144) {
        // ---- pack W layer-1 bf16 fragments for gru DO_MM epilogue ----
        int idx2 = (ob - (GB + 128)) * 256 + tid;  // 0..4095
        int j = idx2 & 7;
        int lane = (idx2 >> 3) & 63;
        int nt = (idx2 >> 9) & 3;
        int kt = idx2 >> 11;
        Wp[idx2] = (short)f2bf(
            W[4096 + (kt * 32 + (lane >> 4) * 8 + j) * 64 + nt * 16 + (lane & 15)]);
    } else {
        int j = tid;
        if (j < 64) {
            bias4[j] = bih[j] + bhh[j];
            bias4[64 + j] = bih[64 + j] + bhh[64 + j];
            bias4[128 + j] = bih[128 + j];
            bias4[192 + j] = bhh[128 + j];
        }
    }
}

// ===== phase 2: block per coarse bin; per-node buckets in LDS, coalesced slab out =====
__global__ __launch_bounds__(256) void bucket_kernel(
        const u32* __restrict__ binned, const u32* __restrict__ binCursor,
        int* __restrict__ deg, u16* __restrict__ srcidx) {
    __shared__ u32 ndeg[256];
    __shared__ __align__(16) u16 nb[256][CAP];  // 32 KB
    int bin = blockIdx.x;
    int tid = threadIdx.x;
    ndeg[tid] = 0;
    __syncthreads();
    int c = (int)binCursor[bin];
    if (c > BCAP) c = BCAP;
    const u32* src = binned + bin * BCAP;
    for (int i = tid; i < c; i += 256) {
        u32 pay = src[i];
        int dl = pay & 255;
        u32 p = atomicAdd(&ndeg[dl], 1u);
        if (p < CAP) nb[dl][p] = (u16)(pay >> 8);
    }
    __syncthreads();
    int node0 = bin * 256;
    int nn = N_NODES - node0;
    if (nn > 256) nn = 256;
    u32x4* dst16 = (u32x4*)(srcidx + (size_t)node0 * CAP);
    const u32x4* src16 = (const u32x4*)nb;
    int tot = nn * 8;
    for (int i = tid; i < tot; i += 256) dst16[i] = src16[i];
    if (tid < nn) {
        u32 d = ndeg[tid];
        deg[node0 + tid] = (int)(d < (u32)CAP ? d : (u32)CAP);
    }
}

// ===== agg: wave per node; half-wave dword gather; OUT: aggf f32 =====
__global__ __launch_bounds__(256) void agg_kernel(const u16* __restrict__ m16,
                                                  const int* __restrict__ deg,
                                                  const u16* __restrict__ srcidx,
                                                  float* __restrict__ aggf) {
    int lane = threadIdx.x & 63;
    int node = blockIdx.x * 4 + (threadIdx.x >> 6);  // grid exact: 50000/4
    int cnt = __builtin_amdgcn_readfirstlane(deg[node]);
    cnt = cnt < CAP ? cnt : CAP;
    int bv = (int)srcidx[node * CAP + lane];
    int half = lane >> 5;
    int l = lane & 31;
    const u32* m32 = (const u32*)m16;
    float a0 = 0.f, a1 = 0.f;
    int k = half;
    for (; k + 6 < cnt; k += 8) {
        int s0 = __shfl(bv, k);
        int s1 = __shfl(bv, k + 2);
        int s2 = __shfl(bv, k + 4);
        int s3 = __shfl(bv, k + 6);
        u32 d0 = m32[s0 * 32 + l];
        u32 d1 = m32[s1 * 32 + l];
        u32 d2 = m32[s2 * 32 + l];
        u32 d3 = m32[s3 * 32 + l];
        a0 += bf2f((u16)d0) + bf2f((u16)d1) + bf2f((u16)d2) + bf2f((u16)d3);
        a1 += bf2f((u16)(d0 >> 16)) + bf2f((u16)(d1 >> 16)) +
              bf2f((u16)(d2 >> 16)) + bf2f((u16)(d3 >> 16));
    }
    for (; k < cnt; k += 2) {
        int s = __shfl(bv, k);
        u32 d = m32[s * 32 + l];
        a0 += bf2f((u16)d);
        a1 += bf2f((u16)(d >> 16));
    }
    a0 += __shfl_xor(a0, 32);
    a1 += __shfl_xor(a1, 32);
    if (half == 0) {  // cols {2l, 2l+1}; coalesced 256B per node
        float2 st;
        st.x = a0;
        st.y = a1;
        ((float2*)aggf)[node * 32 + l] = st;
    }
}

// ===== GRU on 16x16x32 MFMA: wave = 16 rows. Bh (64KB) STAGED IN LDS per block:
// cuts per-gru B L2 traffic 409MB -> 50MB (the measured-floor arithmetic) and makes
// B-reads deterministic ds_read_b128 (lane-stride 16B: conflict-free). A-data and
// gate-blend ho values batch-prefetched. DO_MM epilogue tile ALIASES the staged-Bh
// LDS after a barrier (all waves done reading B). Excess waves (3 in last block)
// clamp instead of early-return so __syncthreads counts stay uniform. =====
template <bool DO_MM>
__global__ __launch_bounds__(256) void gru_kernel(
        const float* __restrict__ aggf, const short* __restrict__ Bh,
        const short* __restrict__ Wp, const float* __restrict__ bias4,
        const float* hin,  // x (L0) or h (L1)
        float* hout, u16* __restrict__ m16,
        const int* __restrict__ batch, float* __restrict__ gsum) {
    __shared__ __align__(16) char lds[65536];  // staged Bh; DO_MM reuses 16.6KB as tiles
    short* BhL = (short*)lds;
    int tid = threadIdx.x;
    // cooperative stage: 64KB = 4096 x 16B, 16 per thread, coalesced
    {
        const u32x4* src = (const u32x4*)Bh;
        u32x4* dst = (u32x4*)lds;
#pragma unroll
        for (int i = 0; i < 16; ++i) dst[i * 256 + tid] = src[i * 256 + tid];
    }
    int lane = tid & 63;
    int wv = tid >> 6;
    int wtask = blockIdx.x * 4 + wv;
    bool active = wtask < GRUT;
    if (!active) wtask = GRUT - 1;  // clamp; stores masked below
    int node0 = wtask * 16;
    int c = lane & 15, q = lane >> 4;  // q in 0..3
    int rowA = node0 + c;

    // ---- prefetch ALL A-data: 4 steps x 8 f32 (batched; latency under the stage) ----
    const float* aggrow = aggf + rowA * 64 + q * 8;
    const float* hinrow = hin + rowA * 64 + q * 8;
    float av0[8], av1[8], hv0[8], hv1[8];
#pragma unroll
    for (int j = 0; j < 8; ++j) av0[j] = aggrow[j];
#pragma unroll
    for (int j = 0; j < 8; ++j) av1[j] = aggrow[32 + j];
#pragma unroll
    for (int j = 0; j < 8; ++j) hv0[j] = hinrow[j];
#pragma unroll
    for (int j = 0; j < 8; ++j) hv1[j] = hinrow[32 + j];

    __syncthreads();  // Bh staged

    f32x4 acc[16];
#pragma unroll
    for (int nt = 0; nt < 16; ++nt) acc[nt] = (f32x4){0.f, 0.f, 0.f, 0.f};

#pragma unroll
    for (int step = 0; step < 4; ++step) {  // logical K: steps 0-1 = agg, 2-3 = h
        const float* tmp = (step == 0) ? av0 : (step == 1) ? av1 : (step == 2) ? hv0 : hv1;
        bf16x8 bfr[8];
#pragma unroll
        for (int nt = 0; nt < 8; ++nt)
            bfr[nt] = *(const bf16x8*)(BhL + (step * 16 + nt) * 512 + lane * 8);
        bf16x8 ah, al;
        split8(tmp, ah, al);
#pragma unroll
        for (int nt = 0; nt < 8; ++nt) {
            acc[nt] = __builtin_amdgcn_mfma_f32_16x16x32_bf16(ah, bfr[nt], acc[nt], 0, 0, 0);
            acc[nt] = __builtin_amdgcn_mfma_f32_16x16x32_bf16(al, bfr[nt], acc[nt], 0, 0, 0);
        }
        bf16x8 bfr2[8];
#pragma unroll
        for (int nt = 0; nt < 8; ++nt)
            bfr2[nt] = *(const bf16x8*)(BhL + (step * 16 + 8 + nt) * 512 + lane * 8);
#pragma unroll
        for (int nt = 0; nt < 8; ++nt) {
            acc[8 + nt] =
                __builtin_amdgcn_mfma_f32_16x16x32_bf16(ah, bfr2[nt], acc[8 + nt], 0, 0, 0);
            acc[8 + nt] =
                __builtin_amdgcn_mfma_f32_16x16x32_bf16(al, bfr2[nt], acc[8 + nt], 0, 0, 0);
        }
    }

    // ---- batch-prefetch gate-blend ho values (16 loads in flight together) ----
    float hov[16];
#pragma unroll
    for (int reg = 0; reg < 4; ++reg)
#pragma unroll
        for (int jt = 0; jt < 4; ++jt)
            hov[reg * 4 + jt] = hin[(node0 + q * 4 + reg) * 64 + jt * 16 + c];

    float* myTile = nullptr;
    if (DO_MM) {
        __syncthreads();  // ALL waves done reading BhL; safe to alias as tiles
        myTile = (float*)lds + wv * 16 * 65;
    }

    // gates: output col j=jt*16+c uses acc {jt, 4+jt, 8+jt, 12+jt} (r, z, i_n, h_n)
    float psum[4] = {0.f, 0.f, 0.f, 0.f};
    int b0 = 0;
    bool uniform = false;
    if (!DO_MM) {
        b0 = batch[node0];
        uniform = (b0 == batch[node0 + 15]);
    }
#pragma unroll
    for (int reg = 0; reg < 4; ++reg) {
        int R = q * 4 + reg;  // local row 0..15
        int row = node0 + R;
#pragma unroll
        for (int jt = 0; jt < 4; ++jt) {
            int j = jt * 16 + c;
            float rr = sigmoidf_(acc[jt][reg] + bias4[j]);
            float zz = sigmoidf_(acc[4 + jt][reg] + bias4[64 + j]);
            float nn = tanhf_(acc[8 + jt][reg] + bias4[128 + j] +
                              rr * (acc[12 + jt][reg] + bias4[192 + j]));
            float ho = hov[reg * 4 + jt];
            float v = (1.f - zz) * nn + zz * ho;
            if (DO_MM) {
                if (active) hout[row * 64 + j] = v;
                myTile[R * 65 + j] = v;  // wave-private slice; garbage ok if !active
            } else {
                float rv = fmaxf(v, 0.f);
                if (uniform) psum[jt] += rv;
                else if (active) atomicAdd(&gsum[batch[row] * 64 + j], rv);
            }
        }
    }

    if (!DO_MM) {
        if (uniform) {
#pragma unroll
            for (int jt = 0; jt < 4; ++jt) {
                psum[jt] += __shfl_xor(psum[jt], 16);
                psum[jt] += __shfl_xor(psum[jt], 32);
            }
            // lane (q,c) emits column q*16+c (covers all 64 cols exactly once)
            float emit = q == 0 ? psum[0] : q == 1 ? psum[1] : q == 2 ? psum[2] : psum[3];
            if (active) atomicAdd(&gsum[b0 * 64 + q * 16 + c], emit);
        }
        return;
    }

    if (DO_MM) {
        // mm next layer: m16[row] = h[row] @ W1 (bf16 x bf16, W1 pre-packed in Wp)
        f32x4 macc[4];
#pragma unroll
        for (int nt = 0; nt < 4; ++nt) macc[nt] = (f32x4){0.f, 0.f, 0.f, 0.f};
#pragma unroll
        for (int kt = 0; kt < 2; ++kt) {
            int k0 = kt * 32 + q * 8;
            bf16x8 wf[4];
#pragma unroll
            for (int nt = 0; nt < 4; ++nt)
                wf[nt] = *(const bf16x8*)(Wp + ((kt * 4 + nt) * 64 + lane) * 8);
            float tmp[8];
#pragma unroll
            for (int j = 0; j < 8; ++j) tmp[j] = myTile[c * 65 + k0 + j];  // 2-way, free
            bf16x8 aa;
            round8(tmp, aa);
#pragma unroll
            for (int nt = 0; nt < 4; ++nt)
                macc[nt] = __builtin_amdgcn_mfma_f32_16x16x32_bf16(aa, wf[nt], macc[nt], 0, 0, 0);
        }
        if (active) {
#pragma unroll
            for (int nt = 0; nt < 4; ++nt)
#pragma unroll
                for (int reg = 0; reg < 4; ++reg)
                    m16[(node0 + q * 4 + reg) * 64 + nt * 16 + c] = f2bf(macc[nt][reg]);
        }
    }
}

// ===== head: block per graph; mean from gsum (32KB) + fc1/relu/fc2/log_softmax =====
__global__ __launch_bounds__(64) void head_kernel(const float* __restrict__ gsum,
                                                  const int* __restrict__ batch,
                                                  const float* __restrict__ fc1w,
                                                  const float* __restrict__ fc1b,
                                                  const float* __restrict__ fc2w,
                                                  const float* __restrict__ fc2b,
                                                  float* __restrict__ out) {
    int g = blockIdx.x;
    int tid = threadIdx.x;
    int lo, hi;
    {
        int a = 0, b = N_NODES;
        while (a < b) { int mid = (a + b) >> 1; if (batch[mid] < g) a = mid + 1; else b = mid; }
        lo = a;
    }
    {
        int a = lo, b = N_NODES;
        while (a < b) { int mid = (a + b) >> 1; if (batch[mid] < g + 1) a = mid + 1; else b = mid; }
        hi = a;
    }
    __shared__ float pv[64];
    __shared__ float s1[32];
    __shared__ float s2[6];
    pv[tid] = gsum[g * 64 + tid] / fmaxf((float)(hi - lo), 1.f);
    __syncthreads();
    if (tid < 32) {
        float a2 = fc1b[tid];
#pragma unroll
        for (int j = 0; j < 64; ++j) a2 = fmaf(pv[j], fc1w[tid * 64 + j], a2);
        s1[tid] = fmaxf(a2, 0.f);
    }
    __syncthreads();
    if (tid < 6) {
        float a2 = fc2b[tid];
#pragma unroll
        for (int j = 0; j < 32; ++j) a2 = fmaf(s1[j], fc2w[tid * 32 + j], a2);
        s2[tid] = a2;
    }
    __syncthreads();
    if (tid == 0) {
        float mx = s2[0];
#pragma unroll
        for (int c = 1; c < 6; ++c) mx = fmaxf(mx, s2[c]);
        float se = 0.f;
#pragma unroll
        for (int c = 0; c < 6; ++c) se += __expf(s2[c] - mx);
        float lse = mx + __logf(se);
#pragma unroll
        for (int c = 0; c < 6; ++c) out[g * 6 + c] = s2[c] - lse;
    }
}

extern "C" void kernel_launch(void* const* d_in, const int* in_sizes, int n_in,
                              void* d_out, int out_size, void* d_ws, size_t ws_size,
                              hipStream_t stream) {
    const float* x    = (const float*)d_in[0];
    const int* ei     = (const int*)d_in[1];
    const int* batch  = (const int*)d_in[2];
    const float* W    = (const float*)d_in[3];
    const float* wih  = (const float*)d_in[4];
    const float* whh  = (const float*)d_in[5];
    const float* bih  = (const float*)d_in[6];
    const float* bhh  = (const float*)d_in[7];
    const float* fc1w = (const float*)d_in[8];
    const float* fc1b = (const float*)d_in[9];
    const float* fc2w = (const float*)d_in[10];
    const float* fc2b = (const float*)d_in[11];
    float* out = (float*)d_out;

    // ---- workspace layout ----
    float* h       = (float*)d_ws;               // 12.8 MB
    float* bias4   = h + N_NODES * D1;           // 256 f
    int* deg       = (int*)(bias4 + 256);        // N_NODES
    u16* srcidx    = (u16*)(deg + N_NODES);      // 6.4 MB
    size_t soff = ((size_t)(srcidx + N_NODES * CAP) + 15) & ~(size_t)15;
    u16* m16    = (u16*)soff;                    // 6.4 MB
    float* aggf = (float*)(m16 + N_NODES * D1);  // 12.8 MB f32 agg
    short* Bh   = (short*)(aggf + N_NODES * D1); // 64 KB
    short* Wp   = Bh + 32768;                    // 8 KB packed W1 frags
    u32* binCursor = (u32*)(Wp + 4096);          // NBINS u32
    float* gsum = (float*)(binCursor + NBINS);   // 32 KB pooled relu-sums (memset w/ cursor)
    // binned runs (4.8 MB) alias the start of aggf: consumed by bucket_kernel,
    // aggf first written by agg_kernel strictly after (kernel boundary).
    u32* binned = (u32*)aggf;

    // one memset covers binCursor (784 B) + gsum (32 KB), contiguous
    hipMemsetAsync(binCursor, 0, NBINS * sizeof(u32) + N_GRAPHS * D1 * sizeof(float), stream);
    // phase 1 (196 fill blocks, start immediately) + mm L0 + Bh/Wp pack + bias
    fused_head_kernel<<<FH_BLOCKS, 256, 0, stream>>>(
        ei, binned, binCursor, x, W, wih, whh, bih, bhh, Bh, Wp, bias4, m16);
    // phase 2: per-bin bucket build, fully coalesced srcidx/deg writes
    bucket_kernel<<<NBINS, 256, 0, stream>>>(binned, binCursor, deg, srcidx);

    // layer 0: agg -> gru (+ fused mm of layer 1 into m16)
    agg_kernel<<<N_NODES / 4, 256, 0, stream>>>(m16, deg, srcidx, aggf);
    gru_kernel<true><<<GB, 256, 0, stream>>>(aggf, Bh, Wp, bias4, x, h, m16, batch, gsum);
    // layer 1: agg -> gru (LAST: fused relu+pool into gsum, no h write)
    agg_kernel<<<N_NODES / 4, 256, 0, stream>>>(m16, deg, srcidx, aggf);
    gru_kernel<false><<<GB, 256, 0, stream>>>(aggf, Bh, Wp, bias4, h, nullptr, nullptr,
                                              batch, gsum);

    head_kernel<<<N_GRAPHS, 64, 0, stream>>>(gsum, batch, fc1w, fc1b, fc2w, fc2b, out);
}

// Round 10
// 197.753 us; speedup vs baseline: 1.4556x; 1.0140x over previous
//
#include <hip/hip_runtime.h>

#define N_NODES 50000
#define N_EDGES 800000
#define D1 64
#define D2 32
#define N_CLASSES 6
#define N_GRAPHS 128
#define CAP 64       // per-node src bucket capacity == wave size; deg max ~45 << 64
#define GB 782       // ceil(50000/64) for 16x16 mm tiles (mm L0 in fused kernel)
#define GRUT 3125    // 50000/16: per-wave gru tasks (16 rows each, exact)

// ---- two-level binned fill ----
#define NBINS 196    // ceil(50000/256): coarse bin = dst>>8 (256 nodes per bin)
#define BCAP 6144    // per-bin global run capacity (mean 4081, >16 sigma headroom)
#define EPB 4096     // edges per phase-1 fill block
#define NFILLB 196   // ceil(800000/4096)
#define LCAP 48      // per-(block,bin) LDS capacity (mean 20.9, ~6 sigma; overflow -> direct)
#define FH_BLOCKS (NFILLB + GB + 128 + 16 + 1)  // fill + mm + Bh pack + Wp pack + bias

typedef unsigned short u16;
typedef unsigned int u32;
typedef __attribute__((ext_vector_type(4))) int i32x4;
typedef __attribute__((ext_vector_type(4))) unsigned int u32x4;
typedef __attribute__((ext_vector_type(8))) short bf16x8;
typedef __attribute__((ext_vector_type(4))) float f32x4;

__device__ __forceinline__ float bf2f(u16 b) {
    u32 u = ((u32)b) << 16;
    float f;
    __builtin_memcpy(&f, &u, 4);
    return f;
}
__device__ __forceinline__ u16 f2bf(float f) {
    u32 u;
    __builtin_memcpy(&u, &f, 4);
    u32 r = (u + 0x7fffu + ((u >> 16) & 1u)) >> 16;
    return (u16)r;
}
__device__ __forceinline__ void split8(const float* v, bf16x8& hi, bf16x8& lo) {
#pragma unroll
    for (int j = 0; j < 8; ++j) {
        u16 h = f2bf(v[j]);
        hi[j] = (short)h;
        lo[j] = (short)f2bf(v[j] - bf2f(h));
    }
}
__device__ __forceinline__ void round8(const float* v, bf16x8& b) {
#pragma unroll
    for (int j = 0; j < 8; ++j) b[j] = (short)f2bf(v[j]);
}
__device__ __forceinline__ float sigmoidf_(float x) {
    return 1.0f / (1.0f + __expf(-x));
}
__device__ __forceinline__ float tanhf_(float x) {
    return 1.0f - 2.0f / (__expf(2.0f * x) + 1.0f);
}

// ===== fused: phase-1 binned edge scatter + pack + mm L0 =====
__global__ __launch_bounds__(256) void fused_head_kernel(
        const int* __restrict__ ei, u32* __restrict__ binned, u32* __restrict__ binCursor,
        const float* __restrict__ x, const float* __restrict__ W,
        const float* __restrict__ wih, const float* __restrict__ whh,
        const float* __restrict__ bih, const float* __restrict__ bhh,
        short* __restrict__ Bh, short* __restrict__ Wp, float* __restrict__ bias4,
        u16* __restrict__ m16) {
    __shared__ u32 cnt[NBINS];
    __shared__ u32 base[NBINS];
    __shared__ u32 buck[NBINS][LCAP];  // 37.6 KB
    int b = blockIdx.x;
    int tid = threadIdx.x;
    if (b < NFILLB) {
        for (int i = tid; i < NBINS; i += 256) cnt[i] = 0;
        __syncthreads();
        int e0 = b * EPB;
        int nq = (min(EPB, N_EDGES - e0)) >> 2;
        const i32x4* s4 = (const i32x4*)ei + (e0 >> 2);
        const i32x4* d4 = (const i32x4*)(ei + N_EDGES) + (e0 >> 2);
        // batch ALL chunk loads ahead of the atomic chains (MLP; R6 lesson)
        i32x4 ss[4], dd[4];
        bool val[4];
#pragma unroll
        for (int ch = 0; ch < 4; ++ch) {
            int i = ch * 256 + tid;
            val[ch] = i < nq;
            if (val[ch]) {
                ss[ch] = s4[i];
                dd[ch] = d4[i];
            }
        }
#pragma unroll
        for (int ch = 0; ch < 4; ++ch) {
            if (val[ch]) {
#pragma unroll
                for (int j = 0; j < 4; ++j) {
                    int s = ss[ch][j];
                    int d = dd[ch][j];
                    int bin = d >> 8;
                    u32 pay = ((u32)s << 8) | (u32)(d & 255);
                    u32 p = atomicAdd(&cnt[bin], 1u);
                    if (p < LCAP) buck[bin][p] = pay;
                    else {
                        u32 q = atomicAdd(&binCursor[bin], 1u);
                        if (q < BCAP) binned[bin * BCAP + q] = pay;
                    }
                }
            }
        }
        __syncthreads();
        int lane = tid & 63, wv = tid >> 6;
        if (lane < 49) {
            int bin = wv * 49 + lane;
            u32 c = cnt[bin];
            c = c < (u32)LCAP ? c : (u32)LCAP;
            base[bin] = atomicAdd(&binCursor[bin], c);
        }
        __syncthreads();
        for (int idx = 0; idx < 49; ++idx) {
            int bin = wv * 49 + idx;
            u32 c = cnt[bin];
            c = c < (u32)LCAP ? c : (u32)LCAP;
            if ((u32)lane < c) {
                u32 pos = base[bin] + lane;
                if (pos < BCAP) binned[bin * BCAP + pos] = buck[bin][lane];
            }
        }
        return;
    }
    int ob = b - NFILLB;
    if (ob < GB) {
        // ---- mm L0: m = x @ W0 (A split bf16, W single bf16; W loads batched) ----
        int lane = tid & 63;
        int wv = tid >> 6;
        int node0 = ob * 64 + wv * 16;
        if (node0 >= N_NODES) return;
        int c0 = lane & 15, qr = lane >> 4;
        f32x4 acc[4];
#pragma unroll
        for (int nt = 0; nt < 4; ++nt) acc[nt] = (f32x4){0.f, 0.f, 0.f, 0.f};
#pragma unroll
        for (int kt = 0; kt < 2; ++kt) {
            int aoff = (node0 + c0) * 64 + kt * 32 + qr * 8;
            float tmp[8];
#pragma unroll
            for (int j = 0; j < 8; ++j) tmp[j] = x[aoff + j];
            int k0 = kt * 32 + qr * 8;
            float wt[4][8];
#pragma unroll
            for (int nt = 0; nt < 4; ++nt)
#pragma unroll
                for (int j = 0; j < 8; ++j) wt[nt][j] = W[(k0 + j) * 64 + nt * 16 + c0];
            bf16x8 ah, al;
            split8(tmp, ah, al);
#pragma unroll
            for (int nt = 0; nt < 4; ++nt) {
                bf16x8 bb;
                round8(wt[nt], bb);
                acc[nt] = __builtin_amdgcn_mfma_f32_16x16x32_bf16(ah, bb, acc[nt], 0, 0, 0);
                acc[nt] = __builtin_amdgcn_mfma_f32_16x16x32_bf16(al, bb, acc[nt], 0, 0, 0);
            }
        }
#pragma unroll
        for (int nt = 0; nt < 4; ++nt)
#pragma unroll
            for (int r = 0; r < 4; ++r)
                m16[(node0 + qr * 4 + r) * 64 + nt * 16 + c0] = f2bf(acc[nt][r]);
    } else if (ob < GB + 128) {
        // ---- pack GRU B (single bf16) in 16x16x32 fragment order ----
        int idx = (ob - GB) * 256 + tid;
        int j = idx & 7;
        int lane = (idx >> 3) & 63;
        int nt = (idx >> 9) & 15;
        int step = idx >> 13;
        int k = step * 32 + (lane >> 4) * 8 + j;
        int n = nt * 16 + (lane & 15);
        int g = n >> 6, d = n & 63;
        float v;
        if (g == 0)      v = (k < 64) ? wih[d * 64 + k] : whh[d * 64 + (k - 64)];
        else if (g == 1) v = (k < 64) ? wih[(64 + d) * 64 + k] : whh[(64 + d) * 64 + (k - 64)];
        else if (g == 2) v = (k < 64) ? wih[(128 + d) * 64 + k] : 0.f;
        else             v = (k < 64) ? 0.f : whh[(128 + d) * 64 + (k - 64)];
        Bh[idx] = (short)f2bf(v);
    } else if (ob < GB + 144) {
        // ---- pack W layer-1 bf16 fragments for gru DO_MM epilogue ----
        int idx2 = (ob - (GB + 128)) * 256 + tid;  // 0..4095
        int j = idx2 & 7;
        int lane = (idx2 >> 3) & 63;
        int nt = (idx2 >> 9) & 3;
        int kt = idx2 >> 11;
        Wp[idx2] = (short)f2bf(
            W[4096 + (kt * 32 + (lane >> 4) * 8 + j) * 64 + nt * 16 + (lane & 15)]);
    } else {
        int j = tid;
        if (j < 64) {
            bias4[j] = bih[j] + bhh[j];
            bias4[64 + j] = bih[64 + j] + bhh[64 + j];
            bias4[128 + j] = bih[128 + j];
            bias4[192 + j] = bhh[128 + j];
        }
    }
}

// ===== phase 2: block per coarse bin; per-node buckets in LDS, coalesced slab out.
// Payload loads batched 4-deep ahead of the LDS-atomic chain. Also zeroes its
// 42-float slice of gsum (replaces the 33KB host memset; gsum first written by gru1). =====
__global__ __launch_bounds__(256) void bucket_kernel(
        const u32* __restrict__ binned, const u32* __restrict__ binCursor,
        int* __restrict__ deg, u16* __restrict__ srcidx, float* __restrict__ gsum) {
    __shared__ u32 ndeg[256];
    __shared__ __align__(16) u16 nb[256][CAP];  // 32 KB
    int bin = blockIdx.x;
    int tid = threadIdx.x;
    ndeg[tid] = 0;
    if (tid < 42) {
        int z = bin * 42 + tid;  // 196*42 = 8232 >= 8192
        if (z < N_GRAPHS * D1) gsum[z] = 0.f;
    }
    __syncthreads();
    int c = (int)binCursor[bin];
    if (c > BCAP) c = BCAP;
    const u32* src = binned + bin * BCAP;
    int i = tid;
    for (; i + 768 < c; i += 1024) {  // 4 loads in flight, then atomic chain
        u32 p0 = src[i];
        u32 p1 = src[i + 256];
        u32 p2 = src[i + 512];
        u32 p3 = src[i + 768];
        u32 q0 = atomicAdd(&ndeg[p0 & 255], 1u);
        if (q0 < CAP) nb[p0 & 255][q0] = (u16)(p0 >> 8);
        u32 q1 = atomicAdd(&ndeg[p1 & 255], 1u);
        if (q1 < CAP) nb[p1 & 255][q1] = (u16)(p1 >> 8);
        u32 q2 = atomicAdd(&ndeg[p2 & 255], 1u);
        if (q2 < CAP) nb[p2 & 255][q2] = (u16)(p2 >> 8);
        u32 q3 = atomicAdd(&ndeg[p3 & 255], 1u);
        if (q3 < CAP) nb[p3 & 255][q3] = (u16)(p3 >> 8);
    }
    for (; i < c; i += 256) {
        u32 pay = src[i];
        int dl = pay & 255;
        u32 p = atomicAdd(&ndeg[dl], 1u);
        if (p < CAP) nb[dl][p] = (u16)(pay >> 8);
    }
    __syncthreads();
    int node0 = bin * 256;
    int nn = N_NODES - node0;
    if (nn > 256) nn = 256;
    u32x4* dst16 = (u32x4*)(srcidx + (size_t)node0 * CAP);
    const u32x4* src16 = (const u32x4*)nb;
    int tot = nn * 8;
    for (int k = tid; k < tot; k += 256) dst16[k] = src16[k];
    if (tid < nn) {
        u32 d = ndeg[tid];
        deg[node0 + tid] = (int)(d < (u32)CAP ? d : (u32)CAP);
    }
}

// ===== agg: wave per node; half-wave dword gather; 16-edge chunk = 8 loads/lane
// in flight (halves exposed L2 latency vs the 8-chunk). Add grouping matches two
// sequential 8-chunks exactly -> bit-identical sums. OUT: aggf f32. =====
__global__ __launch_bounds__(256) void agg_kernel(const u16* __restrict__ m16,
                                                  const int* __restrict__ deg,
                                                  const u16* __restrict__ srcidx,
                                                  float* __restrict__ aggf) {
    int lane = threadIdx.x & 63;
    int node = blockIdx.x * 4 + (threadIdx.x >> 6);  // grid exact: 50000/4
    int cnt = __builtin_amdgcn_readfirstlane(deg[node]);
    cnt = cnt < CAP ? cnt : CAP;
    int bv = (int)srcidx[node * CAP + lane];
    int half = lane >> 5;
    int l = lane & 31;
    const u32* m32 = (const u32*)m16;
    float a0 = 0.f, a1 = 0.f;
    int k = half;
    for (; k + 14 < cnt; k += 16) {
        int s0 = __shfl(bv, k);
        int s1 = __shfl(bv, k + 2);
        int s2 = __shfl(bv, k + 4);
        int s3 = __shfl(bv, k + 6);
        int s4 = __shfl(bv, k + 8);
        int s5 = __shfl(bv, k + 10);
        int s6 = __shfl(bv, k + 12);
        int s7 = __shfl(bv, k + 14);
        u32 d0 = m32[s0 * 32 + l];
        u32 d1 = m32[s1 * 32 + l];
        u32 d2 = m32[s2 * 32 + l];
        u32 d3 = m32[s3 * 32 + l];
        u32 d4 = m32[s4 * 32 + l];
        u32 d5 = m32[s5 * 32 + l];
        u32 d6 = m32[s6 * 32 + l];
        u32 d7 = m32[s7 * 32 + l];
        a0 += bf2f((u16)d0) + bf2f((u16)d1) + bf2f((u16)d2) + bf2f((u16)d3);
        a1 += bf2f((u16)(d0 >> 16)) + bf2f((u16)(d1 >> 16)) +
              bf2f((u16)(d2 >> 16)) + bf2f((u16)(d3 >> 16));
        a0 += bf2f((u16)d4) + bf2f((u16)d5) + bf2f((u16)d6) + bf2f((u16)d7);
        a1 += bf2f((u16)(d4 >> 16)) + bf2f((u16)(d5 >> 16)) +
              bf2f((u16)(d6 >> 16)) + bf2f((u16)(d7 >> 16));
    }
    for (; k + 6 < cnt; k += 8) {
        int s0 = __shfl(bv, k);
        int s1 = __shfl(bv, k + 2);
        int s2 = __shfl(bv, k + 4);
        int s3 = __shfl(bv, k + 6);
        u32 d0 = m32[s0 * 32 + l];
        u32 d1 = m32[s1 * 32 + l];
        u32 d2 = m32[s2 * 32 + l];
        u32 d3 = m32[s3 * 32 + l];
        a0 += bf2f((u16)d0) + bf2f((u16)d1) + bf2f((u16)d2) + bf2f((u16)d3);
        a1 += bf2f((u16)(d0 >> 16)) + bf2f((u16)(d1 >> 16)) +
              bf2f((u16)(d2 >> 16)) + bf2f((u16)(d3 >> 16));
    }
    for (; k < cnt; k += 2) {
        int s = __shfl(bv, k);
        u32 d = m32[s * 32 + l];
        a0 += bf2f((u16)d);
        a1 += bf2f((u16)(d >> 16));
    }
    a0 += __shfl_xor(a0, 32);
    a1 += __shfl_xor(a1, 32);
    if (half == 0) {  // cols {2l, 2l+1}; coalesced 256B per node
        float2 st;
        st.x = a0;
        st.y = a1;
        ((float2*)aggf)[node * 32 + l] = st;
    }
}

// ===== GRU on 16x16x32 MFMA: wave = 16 rows. Bh (64KB) STAGED IN LDS per block;
// A-data and gate-blend ho values batch-prefetched; DO_MM epilogue tile ALIASES
// the staged-Bh LDS after a barrier. Excess waves clamp (uniform barrier counts). =====
template <bool DO_MM>
__global__ __launch_bounds__(256) void gru_kernel(
        const float* __restrict__ aggf, const short* __restrict__ Bh,
        const short* __restrict__ Wp, const float* __restrict__ bias4,
        const float* hin,  // x (L0) or h (L1)
        float* hout, u16* __restrict__ m16,
        const int* __restrict__ batch, float* __restrict__ gsum) {
    __shared__ __align__(16) char lds[65536];  // staged Bh; DO_MM reuses 16.6KB as tiles
    short* BhL = (short*)lds;
    int tid = threadIdx.x;
    // cooperative stage: 64KB = 4096 x 16B, 16 per thread, coalesced
    {
        const u32x4* src = (const u32x4*)Bh;
        u32x4* dst = (u32x4*)lds;
#pragma unroll
        for (int i = 0; i < 16; ++i) dst[i * 256 + tid] = src[i * 256 + tid];
    }
    int lane = tid & 63;
    int wv = tid >> 6;
    int wtask = blockIdx.x * 4 + wv;
    bool active = wtask < GRUT;
    if (!active) wtask = GRUT - 1;  // clamp; stores masked below
    int node0 = wtask * 16;
    int c = lane & 15, q = lane >> 4;  // q in 0..3
    int rowA = node0 + c;

    // ---- prefetch ALL A-data: 4 steps x 8 f32 (batched; latency under the stage) ----
    const float* aggrow = aggf + rowA * 64 + q * 8;
    const float* hinrow = hin + rowA * 64 + q * 8;
    float av0[8], av1[8], hv0[8], hv1[8];
#pragma unroll
    for (int j = 0; j < 8; ++j) av0[j] = aggrow[j];
#pragma unroll
    for (int j = 0; j < 8; ++j) av1[j] = aggrow[32 + j];
#pragma unroll
    for (int j = 0; j < 8; ++j) hv0[j] = hinrow[j];
#pragma unroll
    for (int j = 0; j < 8; ++j) hv1[j] = hinrow[32 + j];

    __syncthreads();  // Bh staged

    f32x4 acc[16];
#pragma unroll
    for (int nt = 0; nt < 16; ++nt) acc[nt] = (f32x4){0.f, 0.f, 0.f, 0.f};

#pragma unroll
    for (int step = 0; step < 4; ++step) {  // logical K: steps 0-1 = agg, 2-3 = h
        const float* tmp = (step == 0) ? av0 : (step == 1) ? av1 : (step == 2) ? hv0 : hv1;
        bf16x8 bfr[8];
#pragma unroll
        for (int nt = 0; nt < 8; ++nt)
            bfr[nt] = *(const bf16x8*)(BhL + (step * 16 + nt) * 512 + lane * 8);
        bf16x8 ah, al;
        split8(tmp, ah, al);
#pragma unroll
        for (int nt = 0; nt < 8; ++nt) {
            acc[nt] = __builtin_amdgcn_mfma_f32_16x16x32_bf16(ah, bfr[nt], acc[nt], 0, 0, 0);
            acc[nt] = __builtin_amdgcn_mfma_f32_16x16x32_bf16(al, bfr[nt], acc[nt], 0, 0, 0);
        }
        bf16x8 bfr2[8];
#pragma unroll
        for (int nt = 0; nt < 8; ++nt)
            bfr2[nt] = *(const bf16x8*)(BhL + (step * 16 + 8 + nt) * 512 + lane * 8);
#pragma unroll
        for (int nt = 0; nt < 8; ++nt) {
            acc[8 + nt] =
                __builtin_amdgcn_mfma_f32_16x16x32_bf16(ah, bfr2[nt], acc[8 + nt], 0, 0, 0);
            acc[8 + nt] =
                __builtin_amdgcn_mfma_f32_16x16x32_bf16(al, bfr2[nt], acc[8 + nt], 0, 0, 0);
        }
    }

    // ---- batch-prefetch gate-blend ho values (16 loads in flight together) ----
    float hov[16];
#pragma unroll
    for (int reg = 0; reg < 4; ++reg)
#pragma unroll
        for (int jt = 0; jt < 4; ++jt)
            hov[reg * 4 + jt] = hin[(node0 + q * 4 + reg) * 64 + jt * 16 + c];

    float* myTile = nullptr;
    if (DO_MM) {
        __syncthreads();  // ALL waves done reading BhL; safe to alias as tiles
        myTile = (float*)lds + wv * 16 * 65;
    }

    // gates: output col j=jt*16+c uses acc {jt, 4+jt, 8+jt, 12+jt} (r, z, i_n, h_n)
    float psum[4] = {0.f, 0.f, 0.f, 0.f};
    int b0 = 0;
    bool uniform = false;
    if (!DO_MM) {
        b0 = batch[node0];
        uniform = (b0 == batch[node0 + 15]);
    }
#pragma unroll
    for (int reg = 0; reg < 4; ++reg) {
        int R = q * 4 + reg;  // local row 0..15
        int row = node0 + R;
#pragma unroll
        for (int jt = 0; jt < 4; ++jt) {
            int j = jt * 16 + c;
            float rr = sigmoidf_(acc[jt][reg] + bias4[j]);
            float zz = sigmoidf_(acc[4 + jt][reg] + bias4[64 + j]);
            float nn = tanhf_(acc[8 + jt][reg] + bias4[128 + j] +
                              rr * (acc[12 + jt][reg] + bias4[192 + j]));
            float ho = hov[reg * 4 + jt];
            float v = (1.f - zz) * nn + zz * ho;
            if (DO_MM) {
                if (active) hout[row * 64 + j] = v;
                myTile[R * 65 + j] = v;  // wave-private slice; garbage ok if !active
            } else {
                float rv = fmaxf(v, 0.f);
                if (uniform) psum[jt] += rv;
                else if (active) atomicAdd(&gsum[batch[row] * 64 + j], rv);
            }
        }
    }

    if (!DO_MM) {
        if (uniform) {
#pragma unroll
            for (int jt = 0; jt < 4; ++jt) {
                psum[jt] += __shfl_xor(psum[jt], 16);
                psum[jt] += __shfl_xor(psum[jt], 32);
            }
            // lane (q,c) emits column q*16+c (covers all 64 cols exactly once)
            float emit = q == 0 ? psum[0] : q == 1 ? psum[1] : q == 2 ? psum[2] : psum[3];
            if (active) atomicAdd(&gsum[b0 * 64 + q * 16 + c], emit);
        }
        return;
    }

    if (DO_MM) {
        // mm next layer: m16[row] = h[row] @ W1 (bf16 x bf16, W1 pre-packed in Wp)
        f32x4 macc[4];
#pragma unroll
        for (int nt = 0; nt < 4; ++nt) macc[nt] = (f32x4){0.f, 0.f, 0.f, 0.f};
#pragma unroll
        for (int kt = 0; kt < 2; ++kt) {
            int k0 = kt * 32 + q * 8;
            bf16x8 wf[4];
#pragma unroll
            for (int nt = 0; nt < 4; ++nt)
                wf[nt] = *(const bf16x8*)(Wp + ((kt * 4 + nt) * 64 + lane) * 8);
            float tmp[8];
#pragma unroll
            for (int j = 0; j < 8; ++j) tmp[j] = myTile[c * 65 + k0 + j];  // 2-way, free
            bf16x8 aa;
            round8(tmp, aa);
#pragma unroll
            for (int nt = 0; nt < 4; ++nt)
                macc[nt] = __builtin_amdgcn_mfma_f32_16x16x32_bf16(aa, wf[nt], macc[nt], 0, 0, 0);
        }
        if (active) {
#pragma unroll
            for (int nt = 0; nt < 4; ++nt)
#pragma unroll
                for (int reg = 0; reg < 4; ++reg)
                    m16[(node0 + q * 4 + reg) * 64 + nt * 16 + c] = f2bf(macc[nt][reg]);
        }
    }
}

// ===== head: block per graph; mean from gsum (32KB) + fc1/relu/fc2/log_softmax =====
__global__ __launch_bounds__(64) void head_kernel(const float* __restrict__ gsum,
                                                  const int* __restrict__ batch,
                                                  const float* __restrict__ fc1w,
                                                  const float* __restrict__ fc1b,
                                                  const float* __restrict__ fc2w,
                                                  const float* __restrict__ fc2b,
                                                  float* __restrict__ out) {
    int g = blockIdx.x;
    int tid = threadIdx.x;
    int lo, hi;
    {
        int a = 0, b = N_NODES;
        while (a < b) { int mid = (a + b) >> 1; if (batch[mid] < g) a = mid + 1; else b = mid; }
        lo = a;
    }
    {
        int a = lo, b = N_NODES;
        while (a < b) { int mid = (a + b) >> 1; if (batch[mid] < g + 1) a = mid + 1; else b = mid; }
        hi = a;
    }
    __shared__ float pv[64];
    __shared__ float s1[32];
    __shared__ float s2[6];
    pv[tid] = gsum[g * 64 + tid] / fmaxf((float)(hi - lo), 1.f);
    __syncthreads();
    if (tid < 32) {
        float a2 = fc1b[tid];
#pragma unroll
        for (int j = 0; j < 64; ++j) a2 = fmaf(pv[j], fc1w[tid * 64 + j], a2);
        s1[tid] = fmaxf(a2, 0.f);
    }
    __syncthreads();
    if (tid < 6) {
        float a2 = fc2b[tid];
#pragma unroll
        for (int j = 0; j < 32; ++j) a2 = fmaf(s1[j], fc2w[tid * 32 + j], a2);
        s2[tid] = a2;
    }
    __syncthreads();
    if (tid == 0) {
        float mx = s2[0];
#pragma unroll
        for (int c = 1; c < 6; ++c) mx = fmaxf(mx, s2[c]);
        float se = 0.f;
#pragma unroll
        for (int c = 0; c < 6; ++c) se += __expf(s2[c] - mx);
        float lse = mx + __logf(se);
#pragma unroll
        for (int c = 0; c < 6; ++c) out[g * 6 + c] = s2[c] - lse;
    }
}

extern "C" void kernel_launch(void* const* d_in, const int* in_sizes, int n_in,
                              void* d_out, int out_size, void* d_ws, size_t ws_size,
                              hipStream_t stream) {
    const float* x    = (const float*)d_in[0];
    const int* ei     = (const int*)d_in[1];
    const int* batch  = (const int*)d_in[2];
    const float* W    = (const float*)d_in[3];
    const float* wih  = (const float*)d_in[4];
    const float* whh  = (const float*)d_in[5];
    const float* bih  = (const float*)d_in[6];
    const float* bhh  = (const float*)d_in[7];
    const float* fc1w = (const float*)d_in[8];
    const float* fc1b = (const float*)d_in[9];
    const float* fc2w = (const float*)d_in[10];
    const float* fc2b = (const float*)d_in[11];
    float* out = (float*)d_out;

    // ---- workspace layout ----
    float* h       = (float*)d_ws;               // 12.8 MB
    float* bias4   = h + N_NODES * D1;           // 256 f
    int* deg       = (int*)(bias4 + 256);        // N_NODES
    u16* srcidx    = (u16*)(deg + N_NODES);      // 6.4 MB
    size_t soff = ((size_t)(srcidx + N_NODES * CAP) + 15) & ~(size_t)15;
    u16* m16    = (u16*)soff;                    // 6.4 MB
    float* aggf = (float*)(m16 + N_NODES * D1);  // 12.8 MB f32 agg
    short* Bh   = (short*)(aggf + N_NODES * D1); // 64 KB
    short* Wp   = Bh + 32768;                    // 8 KB packed W1 frags
    u32* binCursor = (u32*)(Wp + 4096);          // NBINS u32
    float* gsum = (float*)(binCursor + NBINS);   // 32 KB pooled relu-sums (zeroed in bucket)
    // binned runs (4.8 MB) alias the start of aggf: consumed by bucket_kernel,
    // aggf first written by agg_kernel strictly after (kernel boundary).
    u32* binned = (u32*)aggf;

    hipMemsetAsync(binCursor, 0, NBINS * sizeof(u32), stream);
    // phase 1 (196 fill blocks, start immediately) + mm L0 + Bh/Wp pack + bias
    fused_head_kernel<<<FH_BLOCKS, 256, 0, stream>>>(
        ei, binned, binCursor, x, W, wih, whh, bih, bhh, Bh, Wp, bias4, m16);
    // phase 2: per-bin bucket build + gsum zeroing, fully coalesced srcidx/deg writes
    bucket_kernel<<<NBINS, 256, 0, stream>>>(binned, binCursor, deg, srcidx, gsum);

    // layer 0: agg -> gru (+ fused mm of layer 1 into m16)
    agg_kernel<<<N_NODES / 4, 256, 0, stream>>>(m16, deg, srcidx, aggf);
    gru_kernel<true><<<GB, 256, 0, stream>>>(aggf, Bh, Wp, bias4, x, h, m16, batch, gsum);
    // layer 1: agg -> gru (LAST: fused relu+pool into gsum, no h write)
    agg_kernel<<<N_NODES / 4, 256, 0, stream>>>(m16, deg, srcidx, aggf);
    gru_kernel<false><<<GB, 256, 0, stream>>>(aggf, Bh, Wp, bias4, h, nullptr, nullptr,
                                              batch, gsum);

    head_kernel<<<N_GRAPHS, 64, 0, stream>>>(gsum, batch, fc1w, fc1b, fc2w, fc2b, out);
}

// Round 11
// 196.807 us; speedup vs baseline: 1.4626x; 1.0048x over previous
//
#include <hip/hip_runtime.h>

#define N_NODES 50000
#define N_EDGES 800000
#define D1 64
#define D2 32
#define N_CLASSES 6
#define N_GRAPHS 128
#define CAP 64       // per-node src bucket capacity == wave size; deg max ~45 << 64
#define GB 782       // ceil(50000/64) for 16x16 mm tiles (mm L0 in fused kernel)
#define GRUT 3125    // 50000/16: per-wave gru tasks (16 rows each, exact)

// ---- two-level binned fill ----
#define NBINS 196    // ceil(50000/256): coarse bin = dst>>8 (256 nodes per bin)
#define BCAP 6144    // per-bin global run capacity (mean 4081, >16 sigma headroom)
#define EPB 4096     // edges per phase-1 fill block
#define NFILLB 196   // ceil(800000/4096)
#define LCAP 48      // per-(block,bin) LDS capacity (mean 20.9, ~6 sigma; overflow -> direct)
#define FH_BLOCKS (NFILLB + GB + 128 + 16 + 1)  // fill + mm + Bh pack + Wp pack + bias

typedef unsigned short u16;
typedef unsigned int u32;
typedef __attribute__((ext_vector_type(4))) int i32x4;
typedef __attribute__((ext_vector_type(4))) unsigned int u32x4;
typedef __attribute__((ext_vector_type(8))) short bf16x8;
typedef __attribute__((ext_vector_type(4))) float f32x4;

__device__ __forceinline__ float bf2f(u16 b) {
    u32 u = ((u32)b) << 16;
    float f;
    __builtin_memcpy(&f, &u, 4);
    return f;
}
__device__ __forceinline__ u16 f2bf(float f) {
    u32 u;
    __builtin_memcpy(&u, &f, 4);
    u32 r = (u + 0x7fffu + ((u >> 16) & 1u)) >> 16;
    return (u16)r;
}
__device__ __forceinline__ void split8(const float* v, bf16x8& hi, bf16x8& lo) {
#pragma unroll
    for (int j = 0; j < 8; ++j) {
        u16 h = f2bf(v[j]);
        hi[j] = (short)h;
        lo[j] = (short)f2bf(v[j] - bf2f(h));
    }
}
__device__ __forceinline__ void round8(const float* v, bf16x8& b) {
#pragma unroll
    for (int j = 0; j < 8; ++j) b[j] = (short)f2bf(v[j]);
}
__device__ __forceinline__ float sigmoidf_(float x) {
    return 1.0f / (1.0f + __expf(-x));
}
__device__ __forceinline__ float tanhf_(float x) {
    return 1.0f - 2.0f / (__expf(2.0f * x) + 1.0f);
}

// ===== fused: phase-1 binned edge scatter + pack + mm L0 =====
__global__ __launch_bounds__(256) void fused_head_kernel(
        const int* __restrict__ ei, u32* __restrict__ binned, u32* __restrict__ binCursor,
        const float* __restrict__ x, const float* __restrict__ W,
        const float* __restrict__ wih, const float* __restrict__ whh,
        const float* __restrict__ bih, const float* __restrict__ bhh,
        short* __restrict__ Bh, short* __restrict__ Wp, float* __restrict__ bias4,
        u16* __restrict__ m16) {
    __shared__ u32 cnt[NBINS];
    __shared__ u32 base[NBINS];
    __shared__ u32 buck[NBINS][LCAP];  // 37.6 KB
    int b = blockIdx.x;
    int tid = threadIdx.x;
    if (b < NFILLB) {
        for (int i = tid; i < NBINS; i += 256) cnt[i] = 0;
        __syncthreads();
        int e0 = b * EPB;
        int nq = (min(EPB, N_EDGES - e0)) >> 2;
        const i32x4* s4 = (const i32x4*)ei + (e0 >> 2);
        const i32x4* d4 = (const i32x4*)(ei + N_EDGES) + (e0 >> 2);
        // batch ALL chunk loads ahead of the atomic chains (MLP; R6 lesson)
        i32x4 ss[4], dd[4];
        bool val[4];
#pragma unroll
        for (int ch = 0; ch < 4; ++ch) {
            int i = ch * 256 + tid;
            val[ch] = i < nq;
            if (val[ch]) {
                ss[ch] = s4[i];
                dd[ch] = d4[i];
            }
        }
#pragma unroll
        for (int ch = 0; ch < 4; ++ch) {
            if (val[ch]) {
#pragma unroll
                for (int j = 0; j < 4; ++j) {
                    int s = ss[ch][j];
                    int d = dd[ch][j];
                    int bin = d >> 8;
                    u32 pay = ((u32)s << 8) | (u32)(d & 255);
                    u32 p = atomicAdd(&cnt[bin], 1u);
                    if (p < LCAP) buck[bin][p] = pay;
                    else {
                        u32 q = atomicAdd(&binCursor[bin], 1u);
                        if (q < BCAP) binned[bin * BCAP + q] = pay;
                    }
                }
            }
        }
        __syncthreads();
        int lane = tid & 63, wv = tid >> 6;
        if (lane < 49) {
            int bin = wv * 49 + lane;
            u32 c = cnt[bin];
            c = c < (u32)LCAP ? c : (u32)LCAP;
            base[bin] = atomicAdd(&binCursor[bin], c);
        }
        __syncthreads();
        for (int idx = 0; idx < 49; ++idx) {
            int bin = wv * 49 + idx;
            u32 c = cnt[bin];
            c = c < (u32)LCAP ? c : (u32)LCAP;
            if ((u32)lane < c) {
                u32 pos = base[bin] + lane;
                if (pos < BCAP) binned[bin * BCAP + pos] = buck[bin][lane];
            }
        }
        return;
    }
    int ob = b - NFILLB;
    if (ob < GB) {
        // ---- mm L0: m = x @ W0 (A split bf16, W single bf16; W loads batched) ----
        int lane = tid & 63;
        int wv = tid >> 6;
        int node0 = ob * 64 + wv * 16;
        if (node0 >= N_NODES) return;
        int c0 = lane & 15, qr = lane >> 4;
        f32x4 acc[4];
#pragma unroll
        for (int nt = 0; nt < 4; ++nt) acc[nt] = (f32x4){0.f, 0.f, 0.f, 0.f};
#pragma unroll
        for (int kt = 0; kt < 2; ++kt) {
            int aoff = (node0 + c0) * 64 + kt * 32 + qr * 8;
            float tmp[8];
#pragma unroll
            for (int j = 0; j < 8; ++j) tmp[j] = x[aoff + j];
            int k0 = kt * 32 + qr * 8;
            float wt[4][8];
#pragma unroll
            for (int nt = 0; nt < 4; ++nt)
#pragma unroll
                for (int j = 0; j < 8; ++j) wt[nt][j] = W[(k0 + j) * 64 + nt * 16 + c0];
            bf16x8 ah, al;
            split8(tmp, ah, al);
#pragma unroll
            for (int nt = 0; nt < 4; ++nt) {
                bf16x8 bb;
                round8(wt[nt], bb);
                acc[nt] = __builtin_amdgcn_mfma_f32_16x16x32_bf16(ah, bb, acc[nt], 0, 0, 0);
                acc[nt] = __builtin_amdgcn_mfma_f32_16x16x32_bf16(al, bb, acc[nt], 0, 0, 0);
            }
        }
#pragma unroll
        for (int nt = 0; nt < 4; ++nt)
#pragma unroll
            for (int r = 0; r < 4; ++r)
                m16[(node0 + qr * 4 + r) * 64 + nt * 16 + c0] = f2bf(acc[nt][r]);
    } else if (ob < GB + 128) {
        // ---- pack GRU B (single bf16) in 16x16x32 fragment order ----
        int idx = (ob - GB) * 256 + tid;
        int j = idx & 7;
        int lane = (idx >> 3) & 63;
        int nt = (idx >> 9) & 15;
        int step = idx >> 13;
        int k = step * 32 + (lane >> 4) * 8 + j;
        int n = nt * 16 + (lane & 15);
        int g = n >> 6, d = n & 63;
        float v;
        if (g == 0)      v = (k < 64) ? wih[d * 64 + k] : whh[d * 64 + (k - 64)];
        else if (g == 1) v = (k < 64) ? wih[(64 + d) * 64 + k] : whh[(64 + d) * 64 + (k - 64)];
        else if (g == 2) v = (k < 64) ? wih[(128 + d) * 64 + k] : 0.f;
        else             v = (k < 64) ? 0.f : whh[(128 + d) * 64 + (k - 64)];
        Bh[idx] = (short)f2bf(v);
    } else if (ob < GB + 144) {
        // ---- pack W layer-1 bf16 fragments for gru DO_MM epilogue ----
        int idx2 = (ob - (GB + 128)) * 256 + tid;  // 0..4095
        int j = idx2 & 7;
        int lane = (idx2 >> 3) & 63;
        int nt = (idx2 >> 9) & 3;
        int kt = idx2 >> 11;
        Wp[idx2] = (short)f2bf(
            W[4096 + (kt * 32 + (lane >> 4) * 8 + j) * 64 + nt * 16 + (lane & 15)]);
    } else {
        int j = tid;
        if (j < 64) {
            bias4[j] = bih[j] + bhh[j];
            bias4[64 + j] = bih[64 + j] + bhh[64 + j];
            bias4[128 + j] = bih[128 + j];
            bias4[192 + j] = bhh[128 + j];
        }
    }
}

// ===== phase 2: block per coarse bin; per-node buckets in LDS, coalesced slab out.
// Payload loads batched 4-deep ahead of the LDS-atomic chain. Also zeroes its
// 42-float slice of gsum (replaces the 33KB host memset; gsum first written by gru1). =====
__global__ __launch_bounds__(256) void bucket_kernel(
        const u32* __restrict__ binned, const u32* __restrict__ binCursor,
        int* __restrict__ deg, u16* __restrict__ srcidx, float* __restrict__ gsum) {
    __shared__ u32 ndeg[256];
    __shared__ __align__(16) u16 nb[256][CAP];  // 32 KB
    int bin = blockIdx.x;
    int tid = threadIdx.x;
    ndeg[tid] = 0;
    if (tid < 42) {
        int z = bin * 42 + tid;  // 196*42 = 8232 >= 8192
        if (z < N_GRAPHS * D1) gsum[z] = 0.f;
    }
    __syncthreads();
    int c = (int)binCursor[bin];
    if (c > BCAP) c = BCAP;
    const u32* src = binned + bin * BCAP;
    int i = tid;
    for (; i + 768 < c; i += 1024) {  // 4 loads in flight, then atomic chain
        u32 p0 = src[i];
        u32 p1 = src[i + 256];
        u32 p2 = src[i + 512];
        u32 p3 = src[i + 768];
        u32 q0 = atomicAdd(&ndeg[p0 & 255], 1u);
        if (q0 < CAP) nb[p0 & 255][q0] = (u16)(p0 >> 8);
        u32 q1 = atomicAdd(&ndeg[p1 & 255], 1u);
        if (q1 < CAP) nb[p1 & 255][q1] = (u16)(p1 >> 8);
        u32 q2 = atomicAdd(&ndeg[p2 & 255], 1u);
        if (q2 < CAP) nb[p2 & 255][q2] = (u16)(p2 >> 8);
        u32 q3 = atomicAdd(&ndeg[p3 & 255], 1u);
        if (q3 < CAP) nb[p3 & 255][q3] = (u16)(p3 >> 8);
    }
    for (; i < c; i += 256) {
        u32 pay = src[i];
        int dl = pay & 255;
        u32 p = atomicAdd(&ndeg[dl], 1u);
        if (p < CAP) nb[dl][p] = (u16)(pay >> 8);
    }
    __syncthreads();
    int node0 = bin * 256;
    int nn = N_NODES - node0;
    if (nn > 256) nn = 256;
    u32x4* dst16 = (u32x4*)(srcidx + (size_t)node0 * CAP);
    const u32x4* src16 = (const u32x4*)nb;
    int tot = nn * 8;
    for (int k = tid; k < tot; k += 256) dst16[k] = src16[k];
    if (tid < nn) {
        u32 d = ndeg[tid];
        deg[node0 + tid] = (int)(d < (u32)CAP ? d : (u32)CAP);
    }
}

// ===== agg: wave per node; half-wave dword gather; 16-edge chunk = 8 loads/lane
// in flight. OUT: aggf f32. =====
__global__ __launch_bounds__(256) void agg_kernel(const u16* __restrict__ m16,
                                                  const int* __restrict__ deg,
                                                  const u16* __restrict__ srcidx,
                                                  float* __restrict__ aggf) {
    int lane = threadIdx.x & 63;
    int node = blockIdx.x * 4 + (threadIdx.x >> 6);  // grid exact: 50000/4
    int cnt = __builtin_amdgcn_readfirstlane(deg[node]);
    cnt = cnt < CAP ? cnt : CAP;
    int bv = (int)srcidx[node * CAP + lane];
    int half = lane >> 5;
    int l = lane & 31;
    const u32* m32 = (const u32*)m16;
    float a0 = 0.f, a1 = 0.f;
    int k = half;
    for (; k + 14 < cnt; k += 16) {
        int s0 = __shfl(bv, k);
        int s1 = __shfl(bv, k + 2);
        int s2 = __shfl(bv, k + 4);
        int s3 = __shfl(bv, k + 6);
        int s4 = __shfl(bv, k + 8);
        int s5 = __shfl(bv, k + 10);
        int s6 = __shfl(bv, k + 12);
        int s7 = __shfl(bv, k + 14);
        u32 d0 = m32[s0 * 32 + l];
        u32 d1 = m32[s1 * 32 + l];
        u32 d2 = m32[s2 * 32 + l];
        u32 d3 = m32[s3 * 32 + l];
        u32 d4 = m32[s4 * 32 + l];
        u32 d5 = m32[s5 * 32 + l];
        u32 d6 = m32[s6 * 32 + l];
        u32 d7 = m32[s7 * 32 + l];
        a0 += bf2f((u16)d0) + bf2f((u16)d1) + bf2f((u16)d2) + bf2f((u16)d3);
        a1 += bf2f((u16)(d0 >> 16)) + bf2f((u16)(d1 >> 16)) +
              bf2f((u16)(d2 >> 16)) + bf2f((u16)(d3 >> 16));
        a0 += bf2f((u16)d4) + bf2f((u16)d5) + bf2f((u16)d6) + bf2f((u16)d7);
        a1 += bf2f((u16)(d4 >> 16)) + bf2f((u16)(d5 >> 16)) +
              bf2f((u16)(d6 >> 16)) + bf2f((u16)(d7 >> 16));
    }
    for (; k + 6 < cnt; k += 8) {
        int s0 = __shfl(bv, k);
        int s1 = __shfl(bv, k + 2);
        int s2 = __shfl(bv, k + 4);
        int s3 = __shfl(bv, k + 6);
        u32 d0 = m32[s0 * 32 + l];
        u32 d1 = m32[s1 * 32 + l];
        u32 d2 = m32[s2 * 32 + l];
        u32 d3 = m32[s3 * 32 + l];
        a0 += bf2f((u16)d0) + bf2f((u16)d1) + bf2f((u16)d2) + bf2f((u16)d3);
        a1 += bf2f((u16)(d0 >> 16)) + bf2f((u16)(d1 >> 16)) +
              bf2f((u16)(d2 >> 16)) + bf2f((u16)(d3 >> 16));
    }
    for (; k < cnt; k += 2) {
        int s = __shfl(bv, k);
        u32 d = m32[s * 32 + l];
        a0 += bf2f((u16)d);
        a1 += bf2f((u16)(d >> 16));
    }
    a0 += __shfl_xor(a0, 32);
    a1 += __shfl_xor(a1, 32);
    if (half == 0) {  // cols {2l, 2l+1}; coalesced 256B per node
        float2 st;
        st.x = a0;
        st.y = a1;
        ((float2*)aggf)[node * 32 + l] = st;
    }
}

// ===== GRU on 16x16x32 MFMA: wave = 16 rows. Bh staged in TWO 32KB phases
// (steps 0-1, then steps 2-3 into the same LDS): halves the LDS footprint
// 64->32KB, lifting the blocks/CU cap 2->3 (grid-limited) — the kernel is
// latency-bound, so resident waves are the direct latency-hiding multiplier.
// All global loads (A-data + gate-blend ho) issued before the first barrier.
// DO_MM epilogue tile (16.6KB) aliases the staged LDS after a barrier.
// Excess waves clamp (uniform barrier counts). =====
template <bool DO_MM>
__global__ __launch_bounds__(256) void gru_kernel(
        const float* __restrict__ aggf, const short* __restrict__ Bh,
        const short* __restrict__ Wp, const float* __restrict__ bias4,
        const float* hin,  // x (L0) or h (L1)
        float* hout, u16* __restrict__ m16,
        const int* __restrict__ batch, float* __restrict__ gsum) {
    __shared__ __align__(16) char lds[32768];  // half-Bh stage; DO_MM reuses as tiles
    short* BhL = (short*)lds;
    int tid = threadIdx.x;
    // stage half 0 (steps 0-1): 32KB = 2048 x 16B, 8 per thread, coalesced
    {
        const u32x4* src = (const u32x4*)Bh;
        u32x4* dst = (u32x4*)lds;
#pragma unroll
        for (int i = 0; i < 8; ++i) dst[i * 256 + tid] = src[i * 256 + tid];
    }
    int lane = tid & 63;
    int wv = tid >> 6;
    int wtask = blockIdx.x * 4 + wv;
    bool active = wtask < GRUT;
    if (!active) wtask = GRUT - 1;  // clamp; stores masked below
    int node0 = wtask * 16;
    int c = lane & 15, q = lane >> 4;  // q in 0..3
    int rowA = node0 + c;

    // ---- prefetch ALL global A-data + ho (batched; latency under the stage) ----
    const float* aggrow = aggf + rowA * 64 + q * 8;
    const float* hinrow = hin + rowA * 64 + q * 8;
    float av0[8], av1[8], hv0[8], hv1[8];
#pragma unroll
    for (int j = 0; j < 8; ++j) av0[j] = aggrow[j];
#pragma unroll
    for (int j = 0; j < 8; ++j) av1[j] = aggrow[32 + j];
#pragma unroll
    for (int j = 0; j < 8; ++j) hv0[j] = hinrow[j];
#pragma unroll
    for (int j = 0; j < 8; ++j) hv1[j] = hinrow[32 + j];
    float hov[16];
#pragma unroll
    for (int reg = 0; reg < 4; ++reg)
#pragma unroll
        for (int jt = 0; jt < 4; ++jt)
            hov[reg * 4 + jt] = hin[(node0 + q * 4 + reg) * 64 + jt * 16 + c];

    __syncthreads();  // half 0 staged

    f32x4 acc[16];
#pragma unroll
    for (int nt = 0; nt < 16; ++nt) acc[nt] = (f32x4){0.f, 0.f, 0.f, 0.f};

#pragma unroll
    for (int step = 0; step < 2; ++step) {  // steps 0-1: agg
        const float* tmp = (step == 0) ? av0 : av1;
        bf16x8 bfr[8];
#pragma unroll
        for (int nt = 0; nt < 8; ++nt)
            bfr[nt] = *(const bf16x8*)(BhL + (step * 16 + nt) * 512 + lane * 8);
        bf16x8 ah, al;
        split8(tmp, ah, al);
#pragma unroll
        for (int nt = 0; nt < 8; ++nt) {
            acc[nt] = __builtin_amdgcn_mfma_f32_16x16x32_bf16(ah, bfr[nt], acc[nt], 0, 0, 0);
            acc[nt] = __builtin_amdgcn_mfma_f32_16x16x32_bf16(al, bfr[nt], acc[nt], 0, 0, 0);
        }
        bf16x8 bfr2[8];
#pragma unroll
        for (int nt = 0; nt < 8; ++nt)
            bfr2[nt] = *(const bf16x8*)(BhL + (step * 16 + 8 + nt) * 512 + lane * 8);
#pragma unroll
        for (int nt = 0; nt < 8; ++nt) {
            acc[8 + nt] =
                __builtin_amdgcn_mfma_f32_16x16x32_bf16(ah, bfr2[nt], acc[8 + nt], 0, 0, 0);
            acc[8 + nt] =
                __builtin_amdgcn_mfma_f32_16x16x32_bf16(al, bfr2[nt], acc[8 + nt], 0, 0, 0);
        }
    }

    __syncthreads();  // all waves done with half 0
    // stage half 1 (steps 2-3)
    {
        const u32x4* src = (const u32x4*)Bh + 2048;
        u32x4* dst = (u32x4*)lds;
#pragma unroll
        for (int i = 0; i < 8; ++i) dst[i * 256 + tid] = src[i * 256 + tid];
    }
    __syncthreads();  // half 1 staged

#pragma unroll
    for (int step = 0; step < 2; ++step) {  // steps 2-3: h
        const float* tmp = (step == 0) ? hv0 : hv1;
        bf16x8 bfr[8];
#pragma unroll
        for (int nt = 0; nt < 8; ++nt)
            bfr[nt] = *(const bf16x8*)(BhL + (step * 16 + nt) * 512 + lane * 8);
        bf16x8 ah, al;
        split8(tmp, ah, al);
#pragma unroll
        for (int nt = 0; nt < 8; ++nt) {
            acc[nt] = __builtin_amdgcn_mfma_f32_16x16x32_bf16(ah, bfr[nt], acc[nt], 0, 0, 0);
            acc[nt] = __builtin_amdgcn_mfma_f32_16x16x32_bf16(al, bfr[nt], acc[nt], 0, 0, 0);
        }
        bf16x8 bfr2[8];
#pragma unroll
        for (int nt = 0; nt < 8; ++nt)
            bfr2[nt] = *(const bf16x8*)(BhL + (step * 16 + 8 + nt) * 512 + lane * 8);
#pragma unroll
        for (int nt = 0; nt < 8; ++nt) {
            acc[8 + nt] =
                __builtin_amdgcn_mfma_f32_16x16x32_bf16(ah, bfr2[nt], acc[8 + nt], 0, 0, 0);
            acc[8 + nt] =
                __builtin_amdgcn_mfma_f32_16x16x32_bf16(al, bfr2[nt], acc[8 + nt], 0, 0, 0);
        }
    }

    float* myTile = nullptr;
    if (DO_MM) {
        __syncthreads();  // ALL waves done reading BhL; safe to alias as tiles
        myTile = (float*)lds + wv * 16 * 65;  // 16.6KB < 32KB
    }

    // gates: output col j=jt*16+c uses acc {jt, 4+jt, 8+jt, 12+jt} (r, z, i_n, h_n)
    float psum[4] = {0.f, 0.f, 0.f, 0.f};
    int b0 = 0;
    bool uniform = false;
    if (!DO_MM) {
        b0 = batch[node0];
        uniform = (b0 == batch[node0 + 15]);
    }
#pragma unroll
    for (int reg = 0; reg < 4; ++reg) {
        int R = q * 4 + reg;  // local row 0..15
        int row = node0 + R;
#pragma unroll
        for (int jt = 0; jt < 4; ++jt) {
            int j = jt * 16 + c;
            float rr = sigmoidf_(acc[jt][reg] + bias4[j]);
            float zz = sigmoidf_(acc[4 + jt][reg] + bias4[64 + j]);
            float nn = tanhf_(acc[8 + jt][reg] + bias4[128 + j] +
                              rr * (acc[12 + jt][reg] + bias4[192 + j]));
            float ho = hov[reg * 4 + jt];
            float v = (1.f - zz) * nn + zz * ho;
            if (DO_MM) {
                if (active) hout[row * 64 + j] = v;
                myTile[R * 65 + j] = v;  // wave-private slice; garbage ok if !active
            } else {
                float rv = fmaxf(v, 0.f);
                if (uniform) psum[jt] += rv;
                else if (active) atomicAdd(&gsum[batch[row] * 64 + j], rv);
            }
        }
    }

    if (!DO_MM) {
        if (uniform) {
#pragma unroll
            for (int jt = 0; jt < 4; ++jt) {
                psum[jt] += __shfl_xor(psum[jt], 16);
                psum[jt] += __shfl_xor(psum[jt], 32);
            }
            // lane (q,c) emits column q*16+c (covers all 64 cols exactly once)
            float emit = q == 0 ? psum[0] : q == 1 ? psum[1] : q == 2 ? psum[2] : psum[3];
            if (active) atomicAdd(&gsum[b0 * 64 + q * 16 + c], emit);
        }
        return;
    }

    if (DO_MM) {
        // mm next layer: m16[row] = h[row] @ W1 (bf16 x bf16, W1 pre-packed in Wp)
        f32x4 macc[4];
#pragma unroll
        for (int nt = 0; nt < 4; ++nt) macc[nt] = (f32x4){0.f, 0.f, 0.f, 0.f};
#pragma unroll
        for (int kt = 0; kt < 2; ++kt) {
            int k0 = kt * 32 + q * 8;
            bf16x8 wf[4];
#pragma unroll
            for (int nt = 0; nt < 4; ++nt)
                wf[nt] = *(const bf16x8*)(Wp + ((kt * 4 + nt) * 64 + lane) * 8);
            float tmp[8];
#pragma unroll
            for (int j = 0; j < 8; ++j) tmp[j] = myTile[c * 65 + k0 + j];  // 2-way, free
            bf16x8 aa;
            round8(tmp, aa);
#pragma unroll
            for (int nt = 0; nt < 4; ++nt)
                macc[nt] = __builtin_amdgcn_mfma_f32_16x16x32_bf16(aa, wf[nt], macc[nt], 0, 0, 0);
        }
        if (active) {
#pragma unroll
            for (int nt = 0; nt < 4; ++nt)
#pragma unroll
                for (int reg = 0; reg < 4; ++reg)
                    m16[(node0 + q * 4 + reg) * 64 + nt * 16 + c] = f2bf(macc[nt][reg]);
        }
    }
}

// ===== head: block per graph; mean from gsum (32KB) + fc1/relu/fc2/log_softmax =====
__global__ __launch_bounds__(64) void head_kernel(const float* __restrict__ gsum,
                                                  const int* __restrict__ batch,
                                                  const float* __restrict__ fc1w,
                                                  const float* __restrict__ fc1b,
                                                  const float* __restrict__ fc2w,
                                                  const float* __restrict__ fc2b,
                                                  float* __restrict__ out) {
    int g = blockIdx.x;
    int tid = threadIdx.x;
    int lo, hi;
    {
        int a = 0, b = N_NODES;
        while (a < b) { int mid = (a + b) >> 1; if (batch[mid] < g) a = mid + 1; else b = mid; }
        lo = a;
    }
    {
        int a = lo, b = N_NODES;
        while (a < b) { int mid = (a + b) >> 1; if (batch[mid] < g + 1) a = mid + 1; else b = mid; }
        hi = a;
    }
    __shared__ float pv[64];
    __shared__ float s1[32];
    __shared__ float s2[6];
    pv[tid] = gsum[g * 64 + tid] / fmaxf((float)(hi - lo), 1.f);
    __syncthreads();
    if (tid < 32) {
        float a2 = fc1b[tid];
#pragma unroll
        for (int j = 0; j < 64; ++j) a2 = fmaf(pv[j], fc1w[tid * 64 + j], a2);
        s1[tid] = fmaxf(a2, 0.f);
    }
    __syncthreads();
    if (tid < 6) {
        float a2 = fc2b[tid];
#pragma unroll
        for (int j = 0; j < 32; ++j) a2 = fmaf(s1[j], fc2w[tid * 32 + j], a2);
        s2[tid] = a2;
    }
    __syncthreads();
    if (tid == 0) {
        float mx = s2[0];
#pragma unroll
        for (int c = 1; c < 6; ++c) mx = fmaxf(mx, s2[c]);
        float se = 0.f;
#pragma unroll
        for (int c = 0; c < 6; ++c) se += __expf(s2[c] - mx);
        float lse = mx + __logf(se);
#pragma unroll
        for (int c = 0; c < 6; ++c) out[g * 6 + c] = s2[c] - lse;
    }
}

extern "C" void kernel_launch(void* const* d_in, const int* in_sizes, int n_in,
                              void* d_out, int out_size, void* d_ws, size_t ws_size,
                              hipStream_t stream) {
    const float* x    = (const float*)d_in[0];
    const int* ei     = (const int*)d_in[1];
    const int* batch  = (const int*)d_in[2];
    const float* W    = (const float*)d_in[3];
    const float* wih  = (const float*)d_in[4];
    const float* whh  = (const float*)d_in[5];
    const float* bih  = (const float*)d_in[6];
    const float* bhh  = (const float*)d_in[7];
    const float* fc1w = (const float*)d_in[8];
    const float* fc1b = (const float*)d_in[9];
    const float* fc2w = (const float*)d_in[10];
    const float* fc2b = (const float*)d_in[11];
    float* out = (float*)d_out;

    // ---- workspace layout ----
    float* h       = (float*)d_ws;               // 12.8 MB
    float* bias4   = h + N_NODES * D1;           // 256 f
    int* deg       = (int*)(bias4 + 256);        // N_NODES
    u16* srcidx    = (u16*)(deg + N_NODES);      // 6.4 MB
    size_t soff = ((size_t)(srcidx + N_NODES * CAP) + 15) & ~(size_t)15;
    u16* m16    = (u16*)soff;                    // 6.4 MB
    float* aggf = (float*)(m16 + N_NODES * D1);  // 12.8 MB f32 agg
    short* Bh   = (short*)(aggf + N_NODES * D1); // 64 KB
    short* Wp   = Bh + 32768;                    // 8 KB packed W1 frags
    u32* binCursor = (u32*)(Wp + 4096);          // NBINS u32
    float* gsum = (float*)(binCursor + NBINS);   // 32 KB pooled relu-sums (zeroed in bucket)
    // binned runs (4.8 MB) alias the start of aggf: consumed by bucket_kernel,
    // aggf first written by agg_kernel strictly after (kernel boundary).
    u32* binned = (u32*)aggf;

    hipMemsetAsync(binCursor, 0, NBINS * sizeof(u32), stream);
    // phase 1 (196 fill blocks, start immediately) + mm L0 + Bh/Wp pack + bias
    fused_head_kernel<<<FH_BLOCKS, 256, 0, stream>>>(
        ei, binned, binCursor, x, W, wih, whh, bih, bhh, Bh, Wp, bias4, m16);
    // phase 2: per-bin bucket build + gsum zeroing, fully coalesced srcidx/deg writes
    bucket_kernel<<<NBINS, 256, 0, stream>>>(binned, binCursor, deg, srcidx, gsum);

    // layer 0: agg -> gru (+ fused mm of layer 1 into m16)
    agg_kernel<<<N_NODES / 4, 256, 0, stream>>>(m16, deg, srcidx, aggf);
    gru_kernel<true><<<GB, 256, 0, stream>>>(aggf, Bh, Wp, bias4, x, h, m16, batch, gsum);
    // layer 1: agg -> gru (LAST: fused relu+pool into gsum, no h write)
    agg_kernel<<<N_NODES / 4, 256, 0, stream>>>(m16, deg, srcidx, aggf);
    gru_kernel<false><<<GB, 256, 0, stream>>>(aggf, Bh, Wp, bias4, h, nullptr, nullptr,
                                              batch, gsum);

    head_kernel<<<N_GRAPHS, 64, 0, stream>>>(gsum, batch, fc1w, fc1b, fc2w, fc2b, out);
}